// Round 1
// 2964.767 us; speedup vs baseline: 2.4711x; 2.4711x over previous
//
#include <hip/hip_runtime.h>
#include <stdint.h>

#define NN    100000
#define EE    400000
#define NNZK  800000
#define ADJK  400000
#define DDIM  100
#define DOUTK 300

typedef unsigned short u16;
typedef unsigned int   u32;
typedef __attribute__((ext_vector_type(8))) short short8;
typedef __attribute__((ext_vector_type(4))) float f32x4;

__device__ __forceinline__ float bf2f(u16 b) { return __uint_as_float(((u32)b) << 16); }
__device__ __forceinline__ u16 f2bf(float x) {
    u32 u = __float_as_uint(x);
    u32 r = (u + 0x7FFFu + ((u >> 16) & 1u)) >> 16;  // RNE
    return (u16)r;
}
// pack fp32 -> (bf16_hi << 16) | bf16_lo, truncation split: hi+lo == x to ~2^-17 rel
__device__ __forceinline__ u32 pack_hl(float x) {
    u32 u = __float_as_uint(x);
    u32 h = u >> 16;
    float hf = __uint_as_float(h << 16);
    u32 l = __float_as_uint(x - hf) >> 16;
    return (h << 16) | (l & 0xFFFFu);
}
__device__ __forceinline__ float unpack_f32(u32 p) {
    return __uint_as_float(p & 0xFFFF0000u) + __uint_as_float(p << 16);
}
__device__ __forceinline__ void unpack_frag(const u32* __restrict__ src, short8& hi, short8& lo) {
#pragma unroll
    for (int j = 0; j < 8; ++j) {
        u32 u = src[j];
        hi[j] = (short)(u >> 16);
        lo[j] = (short)(u & 0xFFFFu);
    }
}

// ================= CSR building (int atomics only) =================

__global__ __launch_bounds__(256) void k_count(
    const int* __restrict__ idx, int* __restrict__ cnt, int nnz, int kmax)
{
    int i = blockIdx.x * 256 + threadIdx.x;
    if (i >= nnz) return;
    int key = idx[2 * i];
    if (key < 0 || key >= kmax) return;
    atomicAdd(&cnt[key], 1);
}

// base[i] = running offset (wave-aggregated single-counter atomic); cur[i] = base[i]
__global__ __launch_bounds__(256) void k_alloc(
    const int* __restrict__ cnt, int* __restrict__ base, int* __restrict__ cur,
    int* __restrict__ ctr, int n)
{
    int i = blockIdx.x * 256 + threadIdx.x;
    int lane = threadIdx.x & 63;
    int c = (i < n) ? cnt[i] : 0;
    int s = c;
#pragma unroll
    for (int m = 1; m < 64; m <<= 1) {
        int t = __shfl_up(s, m, 64);
        if (lane >= m) s += t;
    }
    int total = __shfl(s, 63, 64);
    int wbase = 0;
    if (lane == 63) wbase = atomicAdd(ctr, total);
    wbase = __shfl(wbase, 63, 64);
    int b = wbase + s - c;   // exclusive within wave
    if (i < n) { base[i] = b; cur[i] = b; }
}

__global__ __launch_bounds__(256) void k_fill(
    const int* __restrict__ idx, const float* __restrict__ val, int* __restrict__ cur,
    int* __restrict__ ocol, float* __restrict__ oval, int* __restrict__ opos,
    int nnz, int kmax)
{
    int i = blockIdx.x * 256 + threadIdx.x;
    if (i >= nnz) return;
    int key = idx[2 * i];
    if (key < 0 || key >= kmax) return;
    int p = atomicAdd(&cur[key], 1);
    ocol[p] = idx[2 * i + 1];
    if (oval) oval[p] = val[i];
    if (opos) opos[i] = p;
}

// ================= rels build: gather + l2norm + bf16 store (CSR-permuted) =================
// one wave per original edge e; writes rels row at adj-CSR position epos[e]
__global__ __launch_bounds__(256) void rels_build(
    const int* __restrict__ base, const int* __restrict__ cnt,
    const int* __restrict__ rk, const float* __restrict__ rv,
    const int* __restrict__ epos, const float* __restrict__ emb,
    u16* __restrict__ rels, int kMax, int nE)
{
    int w = blockIdx.x * 4 + (threadIdx.x >> 6);
    int lane = threadIdx.x & 63;
    if (w >= nE) return;
    int st = base[w], k = cnt[w];
    int d2 = lane + 64;
    float acc1 = 0.f, acc2 = 0.f;
    for (int j = 0; j < k; ++j) {
        int kk = rk[st + j];
        if (kk < 0 || kk >= kMax) continue;
        float v = rv[st + j];
        acc1 += v * emb[(size_t)kk * DDIM + lane];
        if (d2 < DDIM) acc2 += v * emb[(size_t)kk * DDIM + d2];
    }
    float s = acc1 * acc1 + acc2 * acc2;
#pragma unroll
    for (int m = 32; m; m >>= 1) s += __shfl_xor(s, m, 64);
    float sc = 1.f / fmaxf(sqrtf(s), 1e-12f);
    u16* o = rels + (size_t)epos[w] * DDIM;
    o[lane] = f2bf(acc1 * sc);
    if (d2 < DDIM) o[d2] = f2bf(acc2 * sc);
}

// ================= feature mean-aggregation gather (fused tanh) =================
// one wave per row; writes outbuf row cols [0,100) exactly once
__global__ __launch_bounds__(256) void feat_gather(
    const int* __restrict__ base, const int* __restrict__ cnt, const int* __restrict__ fcol,
    const float* __restrict__ emb, float* __restrict__ dst, int colMax, int nRows)
{
    int w = blockIdx.x * 4 + (threadIdx.x >> 6);
    int lane = threadIdx.x & 63;
    if (w >= nRows) return;
    int st = base[w], k = cnt[w];
    int d2 = lane + 64;
    float acc1 = 0.f, acc2 = 0.f;
    for (int j = 0; j < k; ++j) {
        int col = fcol[st + j];
        if (col < 0 || col >= colMax) continue;
        acc1 += emb[(size_t)col * DDIM + lane];
        if (d2 < DDIM) acc2 += emb[(size_t)col * DDIM + d2];
    }
    float inv = k ? 1.f / (float)k : 0.f;
    float* o = dst + (size_t)w * DOUTK;
    o[lane] = tanhf(acc1 * inv);
    if (d2 < DDIM) o[d2] = tanhf(acc2 * inv);
}

// ================= attention: per-row exp(rels . attn[l]) + denominators, reg-resident =================
// one wave per row; att arrays hold UNNORMALIZED exp; den holds 1/sum
__global__ __launch_bounds__(256) void att_fused(
    const int* __restrict__ base, const int* __restrict__ cnt, const u16* __restrict__ rels,
    const float* __restrict__ attn, float* __restrict__ att0, float* __restrict__ att1,
    float* __restrict__ den0, float* __restrict__ den1, int nRows)
{
    int w = blockIdx.x * 4 + (threadIdx.x >> 6);
    int lane = threadIdx.x & 63;
    if (w >= nRows) return;
    int st = base[w], k = cnt[w];
    int d2 = lane + 64;
    float a0 = attn[lane];
    float a1 = attn[DDIM + lane];
    float a0b = 0.f, a1b = 0.f;
    if (d2 < DDIM) { a0b = attn[d2]; a1b = attn[DDIM + d2]; }
    float s0 = 0.f, s1 = 0.f;
    for (int j = 0; j < k; ++j) {
        const u16* r = rels + (size_t)(st + j) * DDIM;
        float r1 = bf2f(r[lane]);
        float r2 = (d2 < DDIM) ? bf2f(r[d2]) : 0.f;
        float p0 = r1 * a0 + r2 * a0b;
        float p1 = r1 * a1 + r2 * a1b;
#pragma unroll
        for (int m = 32; m; m >>= 1) { p0 += __shfl_xor(p0, m, 64); p1 += __shfl_xor(p1, m, 64); }
        float e0 = expf(p0), e1 = expf(p1);
        s0 += e0; s1 += e1;
        if (lane == 0) { att0[st + j] = e0; att1[st + j] = e1; }
    }
    if (lane == 0) {
        den0[w] = k ? 1.f / s0 : 0.f;
        den1[w] = k ? 1.f / s1 : 0.f;
    }
}

// ================= message-passing layer, gather form (fused tanh, zero atomics) =================
// one wave per row: dst[row] = tanh( sum_e att[e]*inv * (f[col] - 2*dot(f,rels)*rels) )
__global__ __launch_bounds__(256) void edge_layer_csr(
    const int* __restrict__ base, const int* __restrict__ cnt, const int* __restrict__ ecol,
    const u16* __restrict__ rels, const float* __restrict__ att, const float* __restrict__ den,
    const float* __restrict__ src, float* __restrict__ dst, int nRows)
{
    int w = blockIdx.x * 4 + (threadIdx.x >> 6);
    int lane = threadIdx.x & 63;
    if (w >= nRows) return;
    int st = base[w], k = cnt[w];
    int d2 = lane + 64;
    float acc1 = 0.f, acc2 = 0.f;
    float inv = den[w];
    for (int j = 0; j < k; ++j) {
        int p = st + j;
        int col = ecol[p];
        if (col < 0 || col >= NN) continue;
        const u16* r = rels + (size_t)p * DDIM;
        const float* f = src + (size_t)col * DOUTK;
        float r1 = bf2f(r[lane]), f1 = f[lane];
        float r2 = 0.f, f2 = 0.f;
        if (d2 < DDIM) { r2 = bf2f(r[d2]); f2 = f[d2]; }
        float pd = f1 * r1 + f2 * r2;
#pragma unroll
        for (int m = 32; m; m >>= 1) pd += __shfl_xor(pd, m, 64);
        float a = att[p] * inv;
        acc1 += a * (f1 - 2.f * pd * r1);
        acc2 += a * (f2 - 2.f * pd * r2);
    }
    float* o = dst + (size_t)w * DOUTK;
    o[lane] = tanhf(acc1);
    if (d2 < DDIM) o[d2] = tanhf(acc2);
}

// ---- inverse norms of proxy rows ----
__global__ __launch_bounds__(64) void proxy_norms(const float* __restrict__ proxy, float* __restrict__ pn)
{
    int k = threadIdx.x;
    if (k >= 64) return;
    float s = 0.f;
    for (int i = 0; i < DOUTK; ++i) { float v = proxy[k * DOUTK + i]; s += v * v; }
    pn[k] = 1.f / fmaxf(sqrtf(s), 1e-12f);
}

// ---- weight prepack kernels: fp32 -> frag-order bf16 [ktile][n][8] ----
// PT[kt<40][n<64][j] = proxy[n][kt*8+j]         (B for pa-GEMM: out @ proxy^T)
__global__ __launch_bounds__(256) void pack_proxyT(const float* __restrict__ p, u16* __restrict__ o)
{
    int t = blockIdx.x * 256 + threadIdx.x;
    if (t >= 40 * 64 * 8) return;
    int j = t & 7, n = (t >> 3) & 63, kt = t >> 9;
    int k = kt * 8 + j;
    o[t] = f2bf((k < 300) ? p[n * 300 + k] : 0.f);
}
// PB[kt<8][n<304][j] = proxy[kt*8+j][n]         (B for pf-GEMM: pa @ proxy)
__global__ __launch_bounds__(256) void pack_proxyB(const float* __restrict__ p, u16* __restrict__ o)
{
    int t = blockIdx.x * 256 + threadIdx.x;
    if (t >= 8 * 304 * 8) return;
    int j = t & 7, n = (t >> 3) % 304, kt = t / (304 * 8);
    int k = kt * 8 + j;
    o[t] = f2bf((k < 64 && n < 300) ? p[k * 300 + n] : 0.f);
}
// GB[kt<40][n<304][j] = gate[kt*8+j][n]         (B for gate-GEMM: pf @ gate)
__global__ __launch_bounds__(256) void pack_gateB(const float* __restrict__ p, u16* __restrict__ o)
{
    int t = blockIdx.x * 256 + threadIdx.x;
    if (t >= 40 * 304 * 8) return;
    int j = t & 7, n = (t >> 3) % 304, kt = t / (304 * 8);
    int k = kt * 8 + j;
    o[t] = f2bf((k < 300 && n < 300) ? p[k * 300 + n] : 0.f);
}

// ---- MFMA epilogue: 16 rows/block; A split hi/lo bf16, B single bf16 ----
// layouts (16x16x32 bf16): A[m=lane&15][k=quad*8+j]; C/D col=lane&15,row=quad*4+reg
__global__ __launch_bounds__(256) void epilogue_mfma(
    const float* __restrict__ outbuf, const u16* __restrict__ PT, const u16* __restrict__ PB,
    const u16* __restrict__ GB, const float* __restrict__ pn, const float* __restrict__ bias,
    float* __restrict__ dout, float alpha, int accumulate)
{
    __shared__ u32 s_o[16][324];   // out, packed hi/lo bf16 (k padded 300..319 = 0)
    __shared__ u32 s_f[16][324];   // pf,  packed hi/lo bf16
    __shared__ float s_pa[16][68];
    __shared__ float s_rn[16], s_pinv[16];

    const int tid = threadIdx.x;
    const int w = tid >> 6, quad = (tid >> 4) & 3, n15 = tid & 15;
    const size_t rowBase = (size_t)blockIdx.x * 16;

    for (int x = tid; x < 16 * 324; x += 256) {
        int r = x / 324, i = x - r * 324;
        float v = (i < 300) ? outbuf[(rowBase + r) * DOUTK + i] : 0.f;
        s_o[r][i] = pack_hl(v);
        if (i >= 300) s_f[r][i] = 0u;
    }
    __syncthreads();

    { // row inverse norms
        int r = tid >> 4, l = tid & 15;
        float s = 0.f;
        for (int i = l; i < 300; i += 16) { float v = unpack_f32(s_o[r][i]); s += v * v; }
#pragma unroll
        for (int m = 8; m; m >>= 1) s += __shfl_xor(s, m, 64);
        if (l == 0) s_rn[r] = 1.f / fmaxf(sqrtf(s), 1e-12f);
    }

    // ---- pa logits: D[16x64] = out @ proxy^T (each wave owns one 16-col tile) ----
    f32x4 accp = {0.f, 0.f, 0.f, 0.f};
    for (int kk = 0; kk < 10; ++kk) {
        short8 ah, al;
        unpack_frag(&s_o[n15][kk * 32 + quad * 8], ah, al);
        short8 b = *(const short8*)(PT + (((kk * 4 + quad) * 64) + (w * 16 + n15)) * 8);
        accp = __builtin_amdgcn_mfma_f32_16x16x32_bf16(ah, b, accp, 0, 0, 0);
        accp = __builtin_amdgcn_mfma_f32_16x16x32_bf16(al, b, accp, 0, 0, 0);
    }
    __syncthreads();   // s_rn ready
    {
        int col = w * 16 + n15;
        float pnc = pn[col];
#pragma unroll
        for (int g = 0; g < 4; ++g) {
            int row = quad * 4 + g;
            s_pa[row][col] = expf(accp[g] * s_rn[row] * pnc);
        }
    }
    __syncthreads();
    { // softmax denominators
        int r = tid >> 4, l = tid & 15;
        float s = s_pa[r][l] + s_pa[r][l + 16] + s_pa[r][l + 32] + s_pa[r][l + 48];
#pragma unroll
        for (int m = 8; m; m >>= 1) s += __shfl_xor(s, m, 64);
        if (l == 0) s_pinv[r] = 1.f / s;
    }
    __syncthreads();

    // ---- pf: T[16x304] = pa_raw @ proxy; pf = out - T * pinv[row] ----
    f32x4 accf[5];
#pragma unroll
    for (int t = 0; t < 5; ++t) accf[t] = (f32x4){0.f, 0.f, 0.f, 0.f};
    for (int kk = 0; kk < 2; ++kk) {
        short8 ah, al;
        {
            const float* src = &s_pa[n15][kk * 32 + quad * 8];
#pragma unroll
            for (int j = 0; j < 8; ++j) {
                float x = src[j];
                u32 h = __float_as_uint(x) >> 16;
                float hf = __uint_as_float(h << 16);
                ah[j] = (short)h;
                al[j] = (short)(__float_as_uint(x - hf) >> 16);
            }
        }
#pragma unroll
        for (int t = 0; t < 5; ++t) {
            int nt = w + 4 * t;
            if (nt < 19) {
                short8 b = *(const short8*)(PB + (((kk * 4 + quad) * 304) + (nt * 16 + n15)) * 8);
                accf[t] = __builtin_amdgcn_mfma_f32_16x16x32_bf16(ah, b, accf[t], 0, 0, 0);
                accf[t] = __builtin_amdgcn_mfma_f32_16x16x32_bf16(al, b, accf[t], 0, 0, 0);
            }
        }
    }
#pragma unroll
    for (int t = 0; t < 5; ++t) {
        int nt = w + 4 * t;
        if (nt < 19) {
            int col = nt * 16 + n15;
#pragma unroll
            for (int g = 0; g < 4; ++g) {
                int row = quad * 4 + g;
                float v = unpack_f32(s_o[row][col]) - accf[t][g] * s_pinv[row];
                s_f[row][col] = pack_hl(v);
            }
        }
    }
    __syncthreads();

    // ---- gate: Z[16x304] = pf @ gate_k ----
    f32x4 accg[5];
#pragma unroll
    for (int t = 0; t < 5; ++t) accg[t] = (f32x4){0.f, 0.f, 0.f, 0.f};
    for (int kk = 0; kk < 10; ++kk) {
        short8 ah, al;
        unpack_frag(&s_f[n15][kk * 32 + quad * 8], ah, al);
#pragma unroll
        for (int t = 0; t < 5; ++t) {
            int nt = w + 4 * t;
            if (nt < 19) {
                short8 b = *(const short8*)(GB + (((kk * 4 + quad) * 304) + (nt * 16 + n15)) * 8);
                accg[t] = __builtin_amdgcn_mfma_f32_16x16x32_bf16(ah, b, accg[t], 0, 0, 0);
                accg[t] = __builtin_amdgcn_mfma_f32_16x16x32_bf16(al, b, accg[t], 0, 0, 0);
            }
        }
    }
    // ---- gated mix + store ----
#pragma unroll
    for (int t = 0; t < 5; ++t) {
        int nt = w + 4 * t;
        if (nt < 19) {
            int col = nt * 16 + n15;
            if (col < 300) {
                float bb = bias[col];
#pragma unroll
                for (int g = 0; g < 4; ++g) {
                    int row = quad * 4 + g;
                    float z = accg[t][g] + bb;
                    float gg = 1.f / (1.f + expf(-z));
                    float ov = unpack_f32(s_o[row][col]);
                    float pv = unpack_f32(s_f[row][col]);
                    float res = (gg * ov + (1.f - gg) * pv) * alpha;
                    float* o = dout + (rowBase + row) * 600 + col;
                    if (accumulate) res += *o;
                    *o = res;
                }
            }
        }
    }
}

extern "C" void kernel_launch(void* const* d_in, const int* in_sizes, int n_in,
                              void* d_out, int out_size, void* d_ws, size_t ws_size,
                              hipStream_t stream)
{
    const int*   adj      = (const int*)d_in[0];
    const int*   r_index  = (const int*)d_in[1];
    const float* r_val    = (const float*)d_in[2];
    const int*   t_index  = (const int*)d_in[3];
    const int*   ent_adj  = (const int*)d_in[4];
    const int*   rel_adj  = (const int*)d_in[5];
    const int*   time_adj = (const int*)d_in[6];
    const float* ent_emb  = (const float*)d_in[7];
    const float* rel_emb  = (const float*)d_in[8];
    const float* time_emb = (const float*)d_in[9];
    const float* e_attn   = (const float*)d_in[10];
    const float* e_gate   = (const float*)d_in[11];
    const float* e_proxy  = (const float*)d_in[12];
    const float* e_bias   = (const float*)d_in[13];
    const float* r_attn   = (const float*)d_in[14];
    const float* r_gate   = (const float*)d_in[15];
    const float* r_proxy  = (const float*)d_in[16];
    const float* r_bias   = (const float*)d_in[17];
    float* out = (float*)d_out;

    char* ws = (char*)d_ws;
    size_t off = 0;
    auto alloc = [&](size_t bytes) { void* p = ws + off; off += (bytes + 255) & ~255ULL; return p; };
    u16* rels     = (u16*)alloc((size_t)EE * DDIM * 2);       // 80 MB
    float* outbuf = (float*)alloc((size_t)NN * DOUTK * 4);    // 120 MB (also r-CSR scratch while dead)
    float* att0   = (float*)alloc((size_t)EE * 4);
    float* att1   = (float*)alloc((size_t)EE * 4);
    float* den0   = (float*)alloc((size_t)NN * 4);
    float* den1   = (float*)alloc((size_t)NN * 4);
    int* adjcnt   = (int*)alloc((size_t)NN * 4);
    int* abase    = (int*)alloc((size_t)NN * 4);
    int* acur     = (int*)alloc((size_t)NN * 4);
    int* ecol     = (int*)alloc((size_t)EE * 4);
    int* epos     = (int*)alloc((size_t)EE * 4);
    int* fcnt     = (int*)alloc((size_t)NN * 4);
    int* fbase    = (int*)alloc((size_t)NN * 4);
    int* fcur     = (int*)alloc((size_t)NN * 4);
    int* fcol     = (int*)alloc((size_t)ADJK * 4);
    int* ctr      = (int*)alloc(256);
    float* pnE    = (float*)alloc(64 * 4);
    float* pnR    = (float*)alloc(64 * 4);
    u16* PT_E     = (u16*)alloc(40 * 64 * 8 * 2);
    u16* PT_R     = (u16*)alloc(40 * 64 * 8 * 2);
    u16* PB_E     = (u16*)alloc(8 * 304 * 8 * 2);
    u16* PB_R     = (u16*)alloc(8 * 304 * 8 * 2);
    u16* GB_E     = (u16*)alloc(40 * 304 * 8 * 2);
    u16* GB_R     = (u16*)alloc(40 * 304 * 8 * 2);

    // r/t sparse-index CSR aliased onto outbuf (outbuf is dead whenever rels is (re)built)
    int*   rcnt  = (int*)outbuf;          // EE ints
    int*   rbase = rcnt + EE;             // EE
    int*   rcur  = rbase + EE;            // EE
    int*   rk    = rcur + EE;             // NNZK
    float* rv    = (float*)(rk + NNZK);   // NNZK   -> total 11.2 MB << 120 MB

    proxy_norms<<<1, 64, 0, stream>>>(e_proxy, pnE);
    proxy_norms<<<1, 64, 0, stream>>>(r_proxy, pnR);
    pack_proxyT<<<80, 256, 0, stream>>>(e_proxy, PT_E);
    pack_proxyT<<<80, 256, 0, stream>>>(r_proxy, PT_R);
    pack_proxyB<<<76, 256, 0, stream>>>(e_proxy, PB_E);
    pack_proxyB<<<76, 256, 0, stream>>>(r_proxy, PB_R);
    pack_gateB<<<380, 256, 0, stream>>>(e_gate, GB_E);
    pack_gateB<<<380, 256, 0, stream>>>(r_gate, GB_R);

    // ---- adj CSR (shared by all encoders), built once ----
    hipMemsetAsync(adjcnt, 0, (size_t)NN * 4, stream);
    hipMemsetAsync(ctr, 0, 4, stream);
    k_count<<<(EE + 255) / 256, 256, 0, stream>>>(adj, adjcnt, EE, NN);
    k_alloc<<<(NN + 255) / 256, 256, 0, stream>>>(adjcnt, abase, acur, ctr, NN);
    k_fill<<<(EE + 255) / 256, 256, 0, stream>>>(adj, nullptr, acur, ecol, nullptr, epos, EE, NN);

    auto build_rels = [&](const int* sp, const float* emb, int kMax) {
        hipMemsetAsync(rcnt, 0, (size_t)EE * 4, stream);
        hipMemsetAsync(ctr, 0, 4, stream);
        k_count<<<(NNZK + 255) / 256, 256, 0, stream>>>(sp, rcnt, NNZK, EE);
        k_alloc<<<(EE + 255) / 256, 256, 0, stream>>>(rcnt, rbase, rcur, ctr, EE);
        k_fill<<<(NNZK + 255) / 256, 256, 0, stream>>>(sp, r_val, rcur, rk, rv, nullptr, NNZK, EE);
        rels_build<<<(EE + 3) / 4, 256, 0, stream>>>(rbase, rcnt, rk, rv, epos, emb, rels, kMax, EE);
    };

    struct Enc {
        const int* fadj; const float* femb; int colMax; const float* attn;
        const u16* PT; const u16* PB; const u16* GB; const float* pn; const float* bias;
        int dcol; float alpha; int accum;
    };
    Enc encs[3] = {
        { ent_adj,  ent_emb,  NN,   e_attn, PT_E, PB_E, GB_E, pnE, e_bias,   0, 1.0f, 0 },
        { rel_adj,  rel_emb,  2000, r_attn, PT_R, PB_R, GB_R, pnR, r_bias, 300, 0.5f, 0 },
        { time_adj, time_emb, 1000, e_attn, PT_E, PB_E, GB_E, pnE, e_bias, 300, 0.5f, 1 },
    };

    const int rw_grid = (NN + 3) / 4;   // wave-per-row grids

    build_rels(r_index, rel_emb, 2000);     // relsR, used by enc 0 and 1
    for (int c = 0; c < 3; ++c) {
        if (c == 2) build_rels(t_index, time_emb, 1000);   // relsT replaces relsR (outbuf dead here)
        const Enc& e = encs[c];

        // feature-adjacency CSR for this encoder
        hipMemsetAsync(fcnt, 0, (size_t)NN * 4, stream);
        hipMemsetAsync(ctr, 0, 4, stream);
        k_count<<<(ADJK + 255) / 256, 256, 0, stream>>>(e.fadj, fcnt, ADJK, NN);
        k_alloc<<<(NN + 255) / 256, 256, 0, stream>>>(fcnt, fbase, fcur, ctr, NN);
        k_fill<<<(ADJK + 255) / 256, 256, 0, stream>>>(e.fadj, nullptr, fcur, fcol, nullptr, nullptr, ADJK, NN);

        feat_gather<<<rw_grid, 256, 0, stream>>>(fbase, fcnt, fcol, e.femb, outbuf, e.colMax, NN);
        att_fused<<<rw_grid, 256, 0, stream>>>(abase, adjcnt, rels, e.attn, att0, att1, den0, den1, NN);
        edge_layer_csr<<<rw_grid, 256, 0, stream>>>(abase, adjcnt, ecol, rels, att0, den0,
                                                    outbuf, outbuf + DDIM, NN);
        edge_layer_csr<<<rw_grid, 256, 0, stream>>>(abase, adjcnt, ecol, rels, att1, den1,
                                                    outbuf + DDIM, outbuf + 2 * DDIM, NN);
        epilogue_mfma<<<NN / 16, 256, 0, stream>>>(outbuf, e.PT, e.PB, e.GB, e.pn, e.bias,
                                                   out + e.dcol, e.alpha, e.accum);
    }
}

// Round 3
// 2806.163 us; speedup vs baseline: 2.6108x; 1.0565x over previous
//
#include <hip/hip_runtime.h>
#include <stdint.h>

#define NN    100000
#define EE    400000
#define NNZK  800000
#define ADJK  400000
#define DDIM  100
#define DOUTK 300

typedef unsigned short u16;
typedef unsigned int   u32;
typedef __attribute__((ext_vector_type(8))) short short8;
typedef __attribute__((ext_vector_type(4))) float f32x4;
typedef __attribute__((ext_vector_type(4))) unsigned short u16x4;

__device__ __forceinline__ float bf2f(u16 b) { return __uint_as_float(((u32)b) << 16); }
__device__ __forceinline__ u16 f2bf(float x) {
    u32 u = __float_as_uint(x);
    u32 r = (u + 0x7FFFu + ((u >> 16) & 1u)) >> 16;  // RNE
    return (u16)r;
}
// truncation hi/lo split: x ~= bf(hi) + bf(lo) to ~2^-17 rel
__device__ __forceinline__ void split_hl(float x, u16& h, u16& l) {
    u32 u = __float_as_uint(x);
    h = (u16)(u >> 16);
    float hf = __uint_as_float(u & 0xFFFF0000u);
    l = (u16)(__float_as_uint(x - hf) >> 16);
}

// ================= CSR building (int atomics only) =================

__global__ __launch_bounds__(256) void k_count(
    const int* __restrict__ idx, int* __restrict__ cnt, int nnz, int kmax)
{
    int i = blockIdx.x * 256 + threadIdx.x;
    if (i >= nnz) return;
    int key = idx[2 * i];
    if (key < 0 || key >= kmax) return;
    atomicAdd(&cnt[key], 1);
}

__global__ __launch_bounds__(256) void k_alloc(
    const int* __restrict__ cnt, int* __restrict__ base, int* __restrict__ cur,
    int* __restrict__ ctr, int n)
{
    int i = blockIdx.x * 256 + threadIdx.x;
    int lane = threadIdx.x & 63;
    int c = (i < n) ? cnt[i] : 0;
    int s = c;
#pragma unroll
    for (int m = 1; m < 64; m <<= 1) {
        int t = __shfl_up(s, m, 64);
        if (lane >= m) s += t;
    }
    int total = __shfl(s, 63, 64);
    int wbase = 0;
    if (lane == 63) wbase = atomicAdd(ctr, total);
    wbase = __shfl(wbase, 63, 64);
    int b = wbase + s - c;   // exclusive within wave
    if (i < n) { base[i] = b; cur[i] = b; }
}

__global__ __launch_bounds__(256) void k_fill(
    const int* __restrict__ idx, const float* __restrict__ val, int* __restrict__ cur,
    int* __restrict__ ocol, float* __restrict__ oval, int* __restrict__ opos,
    int nnz, int kmax)
{
    int i = blockIdx.x * 256 + threadIdx.x;
    if (i >= nnz) return;
    int key = idx[2 * i];
    if (key < 0 || key >= kmax) return;
    int p = atomicAdd(&cur[key], 1);
    ocol[p] = idx[2 * i + 1];
    if (oval) oval[p] = val[i];
    if (opos) opos[i] = p;
}

// ================= rels build: gather + l2norm + bf16 store (CSR-permuted) =================
// one wave per edge; 2 dims/lane (lanes 0..49 active)
__global__ __launch_bounds__(256) void rels_build(
    const int* __restrict__ base, const int* __restrict__ cnt,
    const int* __restrict__ rk, const float* __restrict__ rv,
    const int* __restrict__ epos, const float* __restrict__ emb,
    u16* __restrict__ rels, int kMax, int nE)
{
    int w = blockIdx.x * 4 + (threadIdx.x >> 6);
    int lane = threadIdx.x & 63;
    if (w >= nE) return;
    int st = base[w], k = cnt[w];
    bool act = lane < 50;
    int l2 = lane * 2;
    float acc0 = 0.f, acc1 = 0.f;
    for (int j = 0; j < k; ++j) {
        int kk = rk[st + j];
        if (kk < 0 || kk >= kMax) continue;
        float v = rv[st + j];
        if (act) {
            float2 e = *(const float2*)(emb + (size_t)kk * DDIM + l2);
            acc0 += v * e.x;
            acc1 += v * e.y;
        }
    }
    float s = acc0 * acc0 + acc1 * acc1;
#pragma unroll
    for (int m = 32; m; m >>= 1) s += __shfl_xor(s, m, 64);
    float sc = 1.f / fmaxf(sqrtf(s), 1e-12f);
    if (act) {
        u32 pk = (u32)f2bf(acc0 * sc) | ((u32)f2bf(acc1 * sc) << 16);
        *(u32*)(rels + (size_t)epos[w] * DDIM + l2) = pk;
    }
}

// ================= feature mean-aggregation gather (fused tanh) =================
__global__ __launch_bounds__(256) void feat_gather(
    const int* __restrict__ base, const int* __restrict__ cnt, const int* __restrict__ fcol,
    const float* __restrict__ emb, float* __restrict__ dst, int colMax, int nRows)
{
    int w = blockIdx.x * 4 + (threadIdx.x >> 6);
    int lane = threadIdx.x & 63;
    if (w >= nRows) return;
    int st = base[w], k = cnt[w];
    bool act = lane < 50;
    int l2 = lane * 2;
    float acc0 = 0.f, acc1 = 0.f;
    for (int j = 0; j < k; ++j) {
        int col = fcol[st + j];
        if (col < 0 || col >= colMax) continue;
        if (act) {
            float2 e = *(const float2*)(emb + (size_t)col * DDIM + l2);
            acc0 += e.x;
            acc1 += e.y;
        }
    }
    float inv = k ? 1.f / (float)k : 0.f;
    if (act) {
        float2 o;
        o.x = tanhf(acc0 * inv);
        o.y = tanhf(acc1 * inv);
        *(float2*)(dst + (size_t)w * DOUTK + l2) = o;
    }
}

// ================= fused attention + layer-1 message passing =================
// pass 1: softmax denom for layer0 (reg) + store layer1's exp/denom for later
// pass 2: recompute layer0 logit alongside reflection dot (shared shuffle reduce)
__global__ __launch_bounds__(256) void att_edge(
    const int* __restrict__ base, const int* __restrict__ cnt, const int* __restrict__ ecol,
    const u16* __restrict__ rels, const float* __restrict__ attn,
    float* __restrict__ att1, float* __restrict__ den1,
    const float* __restrict__ src, float* __restrict__ dst, int nRows)
{
    int w = blockIdx.x * 4 + (threadIdx.x >> 6);
    int lane = threadIdx.x & 63;
    if (w >= nRows) return;
    int st = base[w], k = cnt[w];
    bool act = lane < 50;
    int l2 = lane * 2;
    float a00 = 0.f, a01 = 0.f, a10 = 0.f, a11 = 0.f;
    if (act) {
        float2 a0v = *(const float2*)(attn + l2);
        float2 a1v = *(const float2*)(attn + DDIM + l2);
        a00 = a0v.x; a01 = a0v.y; a10 = a1v.x; a11 = a1v.y;
    }
    float s0 = 0.f, s1 = 0.f;
    for (int j = 0; j < k; ++j) {
        float r0 = 0.f, r1 = 0.f;
        if (act) {
            u32 rr = *(const u32*)(rels + (size_t)(st + j) * DDIM + l2);
            r0 = bf2f((u16)rr); r1 = bf2f((u16)(rr >> 16));
        }
        float p0 = r0 * a00 + r1 * a01;
        float p1 = r0 * a10 + r1 * a11;
#pragma unroll
        for (int m = 32; m; m >>= 1) { p0 += __shfl_xor(p0, m, 64); p1 += __shfl_xor(p1, m, 64); }
        float e1v = expf(p1);
        s0 += expf(p0);
        s1 += e1v;
        if (lane == 0) att1[st + j] = e1v;
    }
    float inv0 = k ? 1.f / s0 : 0.f;
    if (lane == 0) den1[w] = k ? 1.f / s1 : 0.f;

    float acc0 = 0.f, acc1 = 0.f;
    for (int j = 0; j < k; ++j) {
        int col = ecol[st + j];
        if (col < 0 || col >= NN) continue;
        float r0 = 0.f, r1 = 0.f, f0 = 0.f, f1 = 0.f;
        if (act) {
            u32 rr = *(const u32*)(rels + (size_t)(st + j) * DDIM + l2);
            r0 = bf2f((u16)rr); r1 = bf2f((u16)(rr >> 16));
            float2 fv = *(const float2*)(src + (size_t)col * DOUTK + l2);
            f0 = fv.x; f1 = fv.y;
        }
        float pd = f0 * r0 + f1 * r1;
        float p0 = r0 * a00 + r1 * a01;
#pragma unroll
        for (int m = 32; m; m >>= 1) { pd += __shfl_xor(pd, m, 64); p0 += __shfl_xor(p0, m, 64); }
        float a = expf(p0) * inv0;
        acc0 += a * (f0 - 2.f * pd * r0);
        acc1 += a * (f1 - 2.f * pd * r1);
    }
    if (act) {
        float2 o;
        o.x = tanhf(acc0);
        o.y = tanhf(acc1);
        *(float2*)(dst + (size_t)w * DOUTK + l2) = o;
    }
}

// ================= layer-2 message passing (uses stored att1/den1) =================
__global__ __launch_bounds__(256) void edge_layer_csr(
    const int* __restrict__ base, const int* __restrict__ cnt, const int* __restrict__ ecol,
    const u16* __restrict__ rels, const float* __restrict__ att, const float* __restrict__ den,
    const float* __restrict__ src, float* __restrict__ dst, int nRows)
{
    int w = blockIdx.x * 4 + (threadIdx.x >> 6);
    int lane = threadIdx.x & 63;
    if (w >= nRows) return;
    int st = base[w], k = cnt[w];
    bool act = lane < 50;
    int l2 = lane * 2;
    float inv = den[w];
    float acc0 = 0.f, acc1 = 0.f;
    for (int j = 0; j < k; ++j) {
        int p = st + j;
        int col = ecol[p];
        if (col < 0 || col >= NN) continue;
        float r0 = 0.f, r1 = 0.f, f0 = 0.f, f1 = 0.f;
        if (act) {
            u32 rr = *(const u32*)(rels + (size_t)p * DDIM + l2);
            r0 = bf2f((u16)rr); r1 = bf2f((u16)(rr >> 16));
            float2 fv = *(const float2*)(src + (size_t)col * DOUTK + l2);
            f0 = fv.x; f1 = fv.y;
        }
        float pd = f0 * r0 + f1 * r1;
#pragma unroll
        for (int m = 32; m; m >>= 1) pd += __shfl_xor(pd, m, 64);
        float a = att[p] * inv;
        acc0 += a * (f0 - 2.f * pd * r0);
        acc1 += a * (f1 - 2.f * pd * r1);
    }
    if (act) {
        float2 o;
        o.x = tanhf(acc0);
        o.y = tanhf(acc1);
        *(float2*)(dst + (size_t)w * DOUTK + l2) = o;
    }
}

// ---- inverse norms of proxy rows ----
__global__ __launch_bounds__(64) void proxy_norms(const float* __restrict__ proxy, float* __restrict__ pn)
{
    int k = threadIdx.x;
    if (k >= 64) return;
    float s = 0.f;
    for (int i = 0; i < DOUTK; ++i) { float v = proxy[k * DOUTK + i]; s += v * v; }
    pn[k] = 1.f / fmaxf(sqrtf(s), 1e-12f);
}

// ---- weight prepack kernels: fp32 -> frag-order bf16 [ktile][n][8] ----
__global__ __launch_bounds__(256) void pack_proxyT(const float* __restrict__ p, u16* __restrict__ o)
{
    int t = blockIdx.x * 256 + threadIdx.x;
    if (t >= 40 * 64 * 8) return;
    int j = t & 7, n = (t >> 3) & 63, kt = t >> 9;
    int k = kt * 8 + j;
    o[t] = f2bf((k < 300) ? p[n * 300 + k] : 0.f);
}
__global__ __launch_bounds__(256) void pack_proxyB(const float* __restrict__ p, u16* __restrict__ o)
{
    int t = blockIdx.x * 256 + threadIdx.x;
    if (t >= 8 * 304 * 8) return;
    int j = t & 7, n = (t >> 3) % 304, kt = t / (304 * 8);
    int k = kt * 8 + j;
    o[t] = f2bf((k < 64 && n < 300) ? p[k * 300 + n] : 0.f);
}
__global__ __launch_bounds__(256) void pack_gateB(const float* __restrict__ p, u16* __restrict__ o)
{
    int t = blockIdx.x * 256 + threadIdx.x;
    if (t >= 40 * 304 * 8) return;
    int j = t & 7, n = (t >> 3) % 304, kt = t / (304 * 8);
    int k = kt * 8 + j;
    o[t] = f2bf((k < 300 && n < 300) ? p[k * 300 + n] : 0.f);
}

// ---- MFMA epilogue: 16 rows/block; hi/lo u16 planes, pf overwrites in place ----
// layouts (16x16x32 bf16): A[m=lane&15][k=quad*8+j]; C/D col=lane&15,row=quad*4+reg
__global__ __launch_bounds__(256) void epilogue_mfma(
    const float* __restrict__ outbuf, const u16* __restrict__ PT, const u16* __restrict__ PB,
    const u16* __restrict__ GB, const float* __restrict__ pn, const float* __restrict__ bias,
    float* __restrict__ dout, float alpha, int accumulate)
{
    __shared__ u16 s_h[16][324];   // hi bf16 plane: out, later pf
    __shared__ u16 s_l[16][324];   // lo bf16 plane
    __shared__ float s_pa[16][68];
    __shared__ float s_rn[16], s_pinv[16];

    const int tid = threadIdx.x;
    const int w = tid >> 6, quad = (tid >> 4) & 3, n15 = tid & 15;
    const size_t rowBase = (size_t)blockIdx.x * 16;

    // zero pad cols 300..323
    for (int x = tid; x < 16 * 24; x += 256) {
        int r = x / 24, c = 300 + (x - (x / 24) * 24);
        s_h[r][c] = 0; s_l[r][c] = 0;
    }
    // main staging: float4 loads, 8B LDS writes per plane
    for (int x = tid; x < 16 * 75; x += 256) {
        int r = x / 75, c4 = x - r * 75, c = c4 * 4;
        float4 v = *(const float4*)(outbuf + (rowBase + r) * DOUTK + c);
        u16 h0, l0, h1, l1, h2, l2v, h3, l3;
        split_hl(v.x, h0, l0);
        split_hl(v.y, h1, l1);
        split_hl(v.z, h2, l2v);
        split_hl(v.w, h3, l3);
        u16x4 hv = {h0, h1, h2, h3};
        u16x4 lv = {l0, l1, l2v, l3};
        *(u16x4*)&s_h[r][c] = hv;
        *(u16x4*)&s_l[r][c] = lv;
    }
    __syncthreads();

    { // row inverse norms
        int r = tid >> 4, l = tid & 15;
        float s = 0.f;
        for (int i = l; i < 300; i += 16) {
            float v = bf2f(s_h[r][i]) + bf2f(s_l[r][i]);
            s += v * v;
        }
#pragma unroll
        for (int m = 8; m; m >>= 1) s += __shfl_xor(s, m, 64);
        if (l == 0) s_rn[r] = 1.f / fmaxf(sqrtf(s), 1e-12f);
    }

    // ---- pa logits: D[16x64] = out @ proxy^T ----
    f32x4 accp = {0.f, 0.f, 0.f, 0.f};
    for (int kk = 0; kk < 10; ++kk) {
        short8 ah = *(const short8*)&s_h[n15][kk * 32 + quad * 8];
        short8 al = *(const short8*)&s_l[n15][kk * 32 + quad * 8];
        short8 b = *(const short8*)(PT + (((kk * 4 + quad) * 64) + (w * 16 + n15)) * 8);
        accp = __builtin_amdgcn_mfma_f32_16x16x32_bf16(ah, b, accp, 0, 0, 0);
        accp = __builtin_amdgcn_mfma_f32_16x16x32_bf16(al, b, accp, 0, 0, 0);
    }
    __syncthreads();   // s_rn ready
    {
        int col = w * 16 + n15;
        float pnc = pn[col];
#pragma unroll
        for (int g = 0; g < 4; ++g) {
            int row = quad * 4 + g;
            s_pa[row][col] = expf(accp[g] * s_rn[row] * pnc);
        }
    }
    __syncthreads();
    { // softmax denominators
        int r = tid >> 4, l = tid & 15;
        float s = s_pa[r][l] + s_pa[r][l + 16] + s_pa[r][l + 32] + s_pa[r][l + 48];
#pragma unroll
        for (int m = 8; m; m >>= 1) s += __shfl_xor(s, m, 64);
        if (l == 0) s_pinv[r] = 1.f / s;
    }
    __syncthreads();

    // ---- pf: T[16x304] = pa_raw @ proxy; pf = out - T*pinv, written IN PLACE over out ----
    f32x4 accf[5];
#pragma unroll
    for (int t = 0; t < 5; ++t) accf[t] = (f32x4){0.f, 0.f, 0.f, 0.f};
    for (int kk = 0; kk < 2; ++kk) {
        short8 ah, al;
        {
            const float* src = &s_pa[n15][kk * 32 + quad * 8];
#pragma unroll
            for (int j = 0; j < 8; ++j) {
                float x = src[j];
                u32 h = __float_as_uint(x) >> 16;
                float hf = __uint_as_float(h << 16);
                ah[j] = (short)h;
                al[j] = (short)(__float_as_uint(x - hf) >> 16);
            }
        }
#pragma unroll
        for (int t = 0; t < 5; ++t) {
            int nt = w + 4 * t;
            if (nt < 19) {
                short8 b = *(const short8*)(PB + (((kk * 4 + quad) * 304) + (nt * 16 + n15)) * 8);
                accf[t] = __builtin_amdgcn_mfma_f32_16x16x32_bf16(ah, b, accf[t], 0, 0, 0);
                accf[t] = __builtin_amdgcn_mfma_f32_16x16x32_bf16(al, b, accf[t], 0, 0, 0);
            }
        }
    }
    float ovr[5][4];   // out values, kept for the final mix (statically indexed)
#pragma unroll
    for (int t = 0; t < 5; ++t) {
        int nt = w + 4 * t;
        if (nt < 19) {
            int col = nt * 16 + n15;
#pragma unroll
            for (int g = 0; g < 4; ++g) {
                int row = quad * 4 + g;
                float ov = bf2f(s_h[row][col]) + bf2f(s_l[row][col]);
                ovr[t][g] = ov;
                float v = ov - accf[t][g] * s_pinv[row];
                u16 hh, ll;
                split_hl(v, hh, ll);
                s_h[row][col] = hh;
                s_l[row][col] = ll;
            }
        }
    }
    __syncthreads();

    // ---- gate: Z[16x304] = pf @ gate_k ----
    f32x4 accg[5];
#pragma unroll
    for (int t = 0; t < 5; ++t) accg[t] = (f32x4){0.f, 0.f, 0.f, 0.f};
    for (int kk = 0; kk < 10; ++kk) {
#pragma unroll
        for (int t = 0; t < 5; ++t) {
            int nt = w + 4 * t;
            if (nt < 19) {
                short8 ah = *(const short8*)&s_h[n15][kk * 32 + quad * 8];
                short8 al = *(const short8*)&s_l[n15][kk * 32 + quad * 8];
                short8 b = *(const short8*)(GB + (((kk * 4 + quad) * 304) + (nt * 16 + n15)) * 8);
                accg[t] = __builtin_amdgcn_mfma_f32_16x16x32_bf16(ah, b, accg[t], 0, 0, 0);
                accg[t] = __builtin_amdgcn_mfma_f32_16x16x32_bf16(al, b, accg[t], 0, 0, 0);
            }
        }
    }
    // ---- gated mix + store (pv read back from planes, ov from regs) ----
#pragma unroll
    for (int t = 0; t < 5; ++t) {
        int nt = w + 4 * t;
        if (nt < 19) {
            int col = nt * 16 + n15;
            if (col < 300) {
                float bb = bias[col];
#pragma unroll
                for (int g = 0; g < 4; ++g) {
                    int row = quad * 4 + g;
                    float z = accg[t][g] + bb;
                    float gg = 1.f / (1.f + expf(-z));
                    float pv = bf2f(s_h[row][col]) + bf2f(s_l[row][col]);
                    float res = (gg * ovr[t][g] + (1.f - gg) * pv) * alpha;
                    float* o = dout + (rowBase + row) * 600 + col;
                    if (accumulate) res += *o;
                    *o = res;
                }
            }
        }
    }
}

extern "C" void kernel_launch(void* const* d_in, const int* in_sizes, int n_in,
                              void* d_out, int out_size, void* d_ws, size_t ws_size,
                              hipStream_t stream)
{
    const int*   adj      = (const int*)d_in[0];
    const int*   r_index  = (const int*)d_in[1];
    const float* r_val    = (const float*)d_in[2];
    const int*   t_index  = (const int*)d_in[3];
    const int*   ent_adj  = (const int*)d_in[4];
    const int*   rel_adj  = (const int*)d_in[5];
    const int*   time_adj = (const int*)d_in[6];
    const float* ent_emb  = (const float*)d_in[7];
    const float* rel_emb  = (const float*)d_in[8];
    const float* time_emb = (const float*)d_in[9];
    const float* e_attn   = (const float*)d_in[10];
    const float* e_gate   = (const float*)d_in[11];
    const float* e_proxy  = (const float*)d_in[12];
    const float* e_bias   = (const float*)d_in[13];
    const float* r_attn   = (const float*)d_in[14];
    const float* r_gate   = (const float*)d_in[15];
    const float* r_proxy  = (const float*)d_in[16];
    const float* r_bias   = (const float*)d_in[17];
    float* out = (float*)d_out;

    char* ws = (char*)d_ws;
    size_t off = 0;
    auto alloc = [&](size_t bytes) { void* p = ws + off; off += (bytes + 255) & ~255ULL; return p; };
    u16* rels     = (u16*)alloc((size_t)EE * DDIM * 2);       // 80 MB
    float* outbuf = (float*)alloc((size_t)NN * DOUTK * 4);    // 120 MB (also r-CSR scratch while dead)
    float* att1   = (float*)alloc((size_t)EE * 4);
    float* den1   = (float*)alloc((size_t)NN * 4);
    int* adjcnt   = (int*)alloc((size_t)NN * 4);
    int* abase    = (int*)alloc((size_t)NN * 4);
    int* acur     = (int*)alloc((size_t)NN * 4);
    int* ecol     = (int*)alloc((size_t)EE * 4);
    int* epos     = (int*)alloc((size_t)EE * 4);
    int* fcnt     = (int*)alloc((size_t)NN * 4);
    int* fbase    = (int*)alloc((size_t)NN * 4);
    int* fcur     = (int*)alloc((size_t)NN * 4);
    int* fcol     = (int*)alloc((size_t)ADJK * 4);
    int* ctr      = (int*)alloc(256);
    float* pnE    = (float*)alloc(64 * 4);
    float* pnR    = (float*)alloc(64 * 4);
    u16* PT_E     = (u16*)alloc(40 * 64 * 8 * 2);
    u16* PT_R     = (u16*)alloc(40 * 64 * 8 * 2);
    u16* PB_E     = (u16*)alloc(8 * 304 * 8 * 2);
    u16* PB_R     = (u16*)alloc(8 * 304 * 8 * 2);
    u16* GB_E     = (u16*)alloc(40 * 304 * 8 * 2);
    u16* GB_R     = (u16*)alloc(40 * 304 * 8 * 2);

    // r/t sparse-index CSR aliased onto outbuf (outbuf is dead whenever rels is (re)built)
    int*   rcnt  = (int*)outbuf;          // EE ints
    int*   rbase = rcnt + EE;             // EE
    int*   rcur  = rbase + EE;            // EE
    int*   rk    = rcur + EE;             // NNZK
    float* rv    = (float*)(rk + NNZK);   // NNZK   -> total 11.2 MB << 120 MB

    proxy_norms<<<1, 64, 0, stream>>>(e_proxy, pnE);
    proxy_norms<<<1, 64, 0, stream>>>(r_proxy, pnR);
    pack_proxyT<<<80, 256, 0, stream>>>(e_proxy, PT_E);
    pack_proxyT<<<80, 256, 0, stream>>>(r_proxy, PT_R);
    pack_proxyB<<<76, 256, 0, stream>>>(e_proxy, PB_E);
    pack_proxyB<<<76, 256, 0, stream>>>(r_proxy, PB_R);
    pack_gateB<<<380, 256, 0, stream>>>(e_gate, GB_E);
    pack_gateB<<<380, 256, 0, stream>>>(r_gate, GB_R);

    // ---- adj CSR (shared by all encoders), built once ----
    hipMemsetAsync(adjcnt, 0, (size_t)NN * 4, stream);
    hipMemsetAsync(ctr, 0, 4, stream);
    k_count<<<(EE + 255) / 256, 256, 0, stream>>>(adj, adjcnt, EE, NN);
    k_alloc<<<(NN + 255) / 256, 256, 0, stream>>>(adjcnt, abase, acur, ctr, NN);
    k_fill<<<(EE + 255) / 256, 256, 0, stream>>>(adj, nullptr, acur, ecol, nullptr, epos, EE, NN);

    auto build_rels = [&](const int* sp, const float* emb, int kMax) {
        hipMemsetAsync(rcnt, 0, (size_t)EE * 4, stream);
        hipMemsetAsync(ctr, 0, 4, stream);
        k_count<<<(NNZK + 255) / 256, 256, 0, stream>>>(sp, rcnt, NNZK, EE);
        k_alloc<<<(EE + 255) / 256, 256, 0, stream>>>(rcnt, rbase, rcur, ctr, EE);
        k_fill<<<(NNZK + 255) / 256, 256, 0, stream>>>(sp, r_val, rcur, rk, rv, nullptr, NNZK, EE);
        rels_build<<<(EE + 3) / 4, 256, 0, stream>>>(rbase, rcnt, rk, rv, epos, emb, rels, kMax, EE);
    };

    struct Enc {
        const int* fadj; const float* femb; int colMax; const float* attn;
        const u16* PT; const u16* PB; const u16* GB; const float* pn; const float* bias;
        int dcol; float alpha; int accum;
    };
    Enc encs[3] = {
        { ent_adj,  ent_emb,  NN,   e_attn, PT_E, PB_E, GB_E, pnE, e_bias,   0, 1.0f, 0 },
        { rel_adj,  rel_emb,  2000, r_attn, PT_R, PB_R, GB_R, pnR, r_bias, 300, 0.5f, 0 },
        { time_adj, time_emb, 1000, e_attn, PT_E, PB_E, GB_E, pnE, e_bias, 300, 0.5f, 1 },
    };

    const int rw_grid = (NN + 3) / 4;   // wave-per-row grids

    build_rels(r_index, rel_emb, 2000);     // relsR, used by enc 0 and 1
    for (int c = 0; c < 3; ++c) {
        if (c == 2) build_rels(t_index, time_emb, 1000);   // relsT replaces relsR (outbuf dead here)
        const Enc& e = encs[c];

        // feature-adjacency CSR for this encoder
        hipMemsetAsync(fcnt, 0, (size_t)NN * 4, stream);
        hipMemsetAsync(ctr, 0, 4, stream);
        k_count<<<(ADJK + 255) / 256, 256, 0, stream>>>(e.fadj, fcnt, ADJK, NN);
        k_alloc<<<(NN + 255) / 256, 256, 0, stream>>>(fcnt, fbase, fcur, ctr, NN);
        k_fill<<<(ADJK + 255) / 256, 256, 0, stream>>>(e.fadj, nullptr, fcur, fcol, nullptr, nullptr, ADJK, NN);

        feat_gather<<<rw_grid, 256, 0, stream>>>(fbase, fcnt, fcol, e.femb, outbuf, e.colMax, NN);
        att_edge<<<rw_grid, 256, 0, stream>>>(abase, adjcnt, ecol, rels, e.attn, att1, den1,
                                              outbuf, outbuf + DDIM, NN);
        edge_layer_csr<<<rw_grid, 256, 0, stream>>>(abase, adjcnt, ecol, rels, att1, den1,
                                                    outbuf + DDIM, outbuf + 2 * DDIM, NN);
        epilogue_mfma<<<NN / 16, 256, 0, stream>>>(outbuf, e.PT, e.PB, e.GB, e.pn, e.bias,
                                                   out + e.dcol, e.alpha, e.accum);
    }
}

// Round 5
// 2517.105 us; speedup vs baseline: 2.9106x; 1.1148x over previous
//
#include <hip/hip_runtime.h>
#include <stdint.h>

#define NN    100000
#define EE    400000
#define NNZK  800000
#define ADJK  400000
#define DDIM  100
#define DOUTK 300

typedef unsigned short u16;
typedef unsigned int   u32;
typedef __attribute__((ext_vector_type(8))) short short8;
typedef __attribute__((ext_vector_type(4))) float f32x4;
typedef __attribute__((ext_vector_type(4))) unsigned short u16x4;

__device__ __forceinline__ float bf2f(u16 b) { return __uint_as_float(((u32)b) << 16); }
__device__ __forceinline__ u16 f2bf(float x) {
    u32 u = __float_as_uint(x);
    u32 r = (u + 0x7FFFu + ((u >> 16) & 1u)) >> 16;  // RNE
    return (u16)r;
}
// truncation hi/lo split: x ~= bf(hi) + bf(lo) to ~2^-17 rel
__device__ __forceinline__ void split_hl(float x, u16& h, u16& l) {
    u32 u = __float_as_uint(x);
    h = (u16)(u >> 16);
    float hf = __uint_as_float(u & 0xFFFF0000u);
    l = (u16)(__float_as_uint(x - hf) >> 16);
}

// ================= CSR building (int atomics only) =================

__global__ __launch_bounds__(256) void k_count(
    const int* __restrict__ idx, int* __restrict__ cnt, int nnz, int kmax)
{
    int i = blockIdx.x * 256 + threadIdx.x;
    if (i >= nnz) return;
    int key = idx[2 * i];
    if (key < 0 || key >= kmax) return;
    atomicAdd(&cnt[key], 1);
}

__global__ __launch_bounds__(256) void k_alloc(
    const int* __restrict__ cnt, int* __restrict__ base, int* __restrict__ cur,
    int* __restrict__ ctr, int n)
{
    int i = blockIdx.x * 256 + threadIdx.x;
    int lane = threadIdx.x & 63;
    int c = (i < n) ? cnt[i] : 0;
    int s = c;
#pragma unroll
    for (int m = 1; m < 64; m <<= 1) {
        int t = __shfl_up(s, m, 64);
        if (lane >= m) s += t;
    }
    int total = __shfl(s, 63, 64);
    int wbase = 0;
    if (lane == 63) wbase = atomicAdd(ctr, total);
    wbase = __shfl(wbase, 63, 64);
    int b = wbase + s - c;   // exclusive within wave
    if (i < n) { base[i] = b; cur[i] = b; }
}

__global__ __launch_bounds__(256) void k_fill(
    const int* __restrict__ idx, const float* __restrict__ val, int* __restrict__ cur,
    int* __restrict__ ocol, float* __restrict__ oval, int* __restrict__ opos,
    int nnz, int kmax)
{
    int i = blockIdx.x * 256 + threadIdx.x;
    if (i >= nnz) return;
    int key = idx[2 * i];
    if (key < 0 || key >= kmax) return;
    int p = atomicAdd(&cur[key], 1);
    ocol[p] = idx[2 * i + 1];
    if (oval) oval[p] = val[i];
    if (opos) opos[i] = p;
}

// ================= rels build + fused attention logits =================
// one wave per edge; gathers val*emb, l2-normalizes (regs), writes bf16 rels
// at CSR position, AND computes exp(dot(rels, attn[l])) for up to two attn
// sets, accumulating per-row softmax denominators via float atomics (lane 0).
__global__ __launch_bounds__(256) void rels_build(
    const int* __restrict__ base, const int* __restrict__ cnt,
    const int* __restrict__ rk, const float* __restrict__ rv,
    const int* __restrict__ epos, const int* __restrict__ adjr,
    const float* __restrict__ emb, u16* __restrict__ rels,
    const float* __restrict__ attnA, float* __restrict__ attA0, float* __restrict__ attA1,
    float* __restrict__ denA0, float* __restrict__ denA1,
    const float* __restrict__ attnB, float* __restrict__ attB0, float* __restrict__ attB1,
    float* __restrict__ denB0, float* __restrict__ denB1,
    int kMax, int nE)
{
    int w = blockIdx.x * 4 + (threadIdx.x >> 6);
    int lane = threadIdx.x & 63;
    if (w >= nE) return;
    int st = base[w], k = cnt[w];
    bool act = lane < 50;
    bool hasB = (attnB != nullptr);
    int l2 = lane * 2;
    float acc0 = 0.f, acc1 = 0.f;
    for (int j = 0; j < k; ++j) {
        int kk = rk[st + j];
        if (kk < 0 || kk >= kMax) continue;
        float v = rv[st + j];
        if (act) {
            float2 e = *(const float2*)(emb + (size_t)kk * DDIM + l2);
            acc0 += v * e.x;
            acc1 += v * e.y;
        }
    }
    float aA00 = 0.f, aA01 = 0.f, aA10 = 0.f, aA11 = 0.f;
    float aB00 = 0.f, aB01 = 0.f, aB10 = 0.f, aB11 = 0.f;
    if (act) {
        float2 a0 = *(const float2*)(attnA + l2);
        float2 a1 = *(const float2*)(attnA + DDIM + l2);
        aA00 = a0.x; aA01 = a0.y; aA10 = a1.x; aA11 = a1.y;
        if (hasB) {
            float2 b0 = *(const float2*)(attnB + l2);
            float2 b1 = *(const float2*)(attnB + DDIM + l2);
            aB00 = b0.x; aB01 = b0.y; aB10 = b1.x; aB11 = b1.y;
        }
    }
    float s   = acc0 * acc0 + acc1 * acc1;
    float dA0 = acc0 * aA00 + acc1 * aA01;
    float dA1 = acc0 * aA10 + acc1 * aA11;
#pragma unroll
    for (int m = 32; m; m >>= 1) {
        s   += __shfl_xor(s, m, 64);
        dA0 += __shfl_xor(dA0, m, 64);
        dA1 += __shfl_xor(dA1, m, 64);
    }
    float dB0 = 0.f, dB1 = 0.f;
    if (hasB) {
        dB0 = acc0 * aB00 + acc1 * aB01;
        dB1 = acc0 * aB10 + acc1 * aB11;
#pragma unroll
        for (int m = 32; m; m >>= 1) {
            dB0 += __shfl_xor(dB0, m, 64);
            dB1 += __shfl_xor(dB1, m, 64);
        }
    }
    float sc = 1.f / fmaxf(sqrtf(s), 1e-12f);
    int ep = epos[w];
    if (act) {
        u32 pk = (u32)f2bf(acc0 * sc) | ((u32)f2bf(acc1 * sc) << 16);
        *(u32*)(rels + (size_t)ep * DDIM + l2) = pk;
    }
    if (lane == 0) {
        int row = adjr[2 * w];
        bool rok = (row >= 0 && row < NN);
        float eA0 = __expf(dA0 * sc), eA1 = __expf(dA1 * sc);
        attA0[ep] = eA0; attA1[ep] = eA1;
        if (rok) { atomicAdd(&denA0[row], eA0); atomicAdd(&denA1[row], eA1); }
        if (hasB) {
            float eB0 = __expf(dB0 * sc), eB1 = __expf(dB1 * sc);
            attB0[ep] = eB0; attB1[ep] = eB1;
            if (rok) { atomicAdd(&denB0[row], eB0); atomicAdd(&denB1[row], eB1); }
        }
    }
}

// ================= feature mean-aggregation gather (fused tanh) =================
__global__ __launch_bounds__(256) void feat_gather(
    const int* __restrict__ base, const int* __restrict__ cnt, const int* __restrict__ fcol,
    const float* __restrict__ emb, float* __restrict__ dst, int colMax, int nRows)
{
    int w = blockIdx.x * 4 + (threadIdx.x >> 6);
    int lane = threadIdx.x & 63;
    if (w >= nRows) return;
    int st = base[w], k = cnt[w];
    bool act = lane < 50;
    int l2 = lane * 2;
    float acc0 = 0.f, acc1 = 0.f;
    for (int j = 0; j < k; ++j) {
        int col = fcol[st + j];
        if (col < 0 || col >= colMax) continue;
        if (act) {
            float2 e = *(const float2*)(emb + (size_t)col * DDIM + l2);
            acc0 += e.x;
            acc1 += e.y;
        }
    }
    float inv = k ? 1.f / (float)k : 0.f;
    if (act) {
        float2 o;
        o.x = tanhf(acc0 * inv);
        o.y = tanhf(acc1 * inv);
        *(float2*)(dst + (size_t)w * DOUTK + l2) = o;
    }
}

// ================= message-passing layer (gather, precomputed att/den) ========
// dst[row] = tanh( sum_e att[e]/den[row] * (f[col] - 2*dot(f,rels)*rels) )
__global__ __launch_bounds__(256) void mp_layer(
    const int* __restrict__ base, const int* __restrict__ cnt, const int* __restrict__ ecol,
    const u16* __restrict__ rels, const float* __restrict__ att, const float* __restrict__ den,
    const float* __restrict__ src, float* __restrict__ dst, int nRows)
{
    int w = blockIdx.x * 4 + (threadIdx.x >> 6);
    int lane = threadIdx.x & 63;
    if (w >= nRows) return;
    int st = base[w], k = cnt[w];
    bool act = lane < 50;
    int l2 = lane * 2;
    float d = den[w];
    float inv = (d > 0.f) ? 1.f / d : 0.f;
    float acc0 = 0.f, acc1 = 0.f;
    for (int j = 0; j < k; ++j) {
        int p = st + j;
        int col = ecol[p];
        if (col < 0 || col >= NN) continue;
        float r0 = 0.f, r1 = 0.f, f0 = 0.f, f1 = 0.f;
        if (act) {
            u32 rr = *(const u32*)(rels + (size_t)p * DDIM + l2);
            r0 = bf2f((u16)rr); r1 = bf2f((u16)(rr >> 16));
            float2 fv = *(const float2*)(src + (size_t)col * DOUTK + l2);
            f0 = fv.x; f1 = fv.y;
        }
        float pd = f0 * r0 + f1 * r1;
#pragma unroll
        for (int m = 32; m; m >>= 1) pd += __shfl_xor(pd, m, 64);
        float a = att[p] * inv;
        acc0 += a * (f0 - 2.f * pd * r0);
        acc1 += a * (f1 - 2.f * pd * r1);
    }
    if (act) {
        float2 o;
        o.x = tanhf(acc0);
        o.y = tanhf(acc1);
        *(float2*)(dst + (size_t)w * DOUTK + l2) = o;
    }
}

// ---- inverse norms of proxy rows ----
__global__ __launch_bounds__(64) void proxy_norms(const float* __restrict__ proxy, float* __restrict__ pn)
{
    int k = threadIdx.x;
    if (k >= 64) return;
    float s = 0.f;
    for (int i = 0; i < DOUTK; ++i) { float v = proxy[k * DOUTK + i]; s += v * v; }
    pn[k] = 1.f / fmaxf(sqrtf(s), 1e-12f);
}

// ---- weight prepack kernels: fp32 -> frag-order bf16 [ktile][n][8] ----
__global__ __launch_bounds__(256) void pack_proxyT(const float* __restrict__ p, u16* __restrict__ o)
{
    int t = blockIdx.x * 256 + threadIdx.x;
    if (t >= 40 * 64 * 8) return;
    int j = t & 7, n = (t >> 3) & 63, kt = t >> 9;
    int k = kt * 8 + j;
    o[t] = f2bf((k < 300) ? p[n * 300 + k] : 0.f);
}
__global__ __launch_bounds__(256) void pack_proxyB(const float* __restrict__ p, u16* __restrict__ o)
{
    int t = blockIdx.x * 256 + threadIdx.x;
    if (t >= 8 * 304 * 8) return;
    int j = t & 7, n = (t >> 3) % 304, kt = t / (304 * 8);
    int k = kt * 8 + j;
    o[t] = f2bf((k < 64 && n < 300) ? p[k * 300 + n] : 0.f);
}
__global__ __launch_bounds__(256) void pack_gateB(const float* __restrict__ p, u16* __restrict__ o)
{
    int t = blockIdx.x * 256 + threadIdx.x;
    if (t >= 40 * 304 * 8) return;
    int j = t & 7, n = (t >> 3) % 304, kt = t / (304 * 8);
    int k = kt * 8 + j;
    o[t] = f2bf((k < 300 && n < 300) ? p[k * 300 + n] : 0.f);
}

// ---- MFMA epilogue: 16 rows/block, 512 threads (8 waves), 3 tiles/wave ----
// layouts (16x16x32 bf16): A[m=lane&15][k=quad*8+j]; C/D col=lane&15,row=quad*4+reg
// waves 0-3: pa GEMM; waves 4-7: row norms (concurrent). Final mix uses
// res = pv + gate*(accf*pinv) (ov never stored: ov-pv == T*pinv).
__global__ __launch_bounds__(512, 6) void epilogue_mfma(
    const float* __restrict__ outbuf, const u16* __restrict__ PT, const u16* __restrict__ PB,
    const u16* __restrict__ GB, const float* __restrict__ pn, const float* __restrict__ bias,
    float* __restrict__ dout, float alpha, int accumulate)
{
    __shared__ u16 s_h[16][324];   // hi bf16 plane: out, later pf
    __shared__ u16 s_l[16][324];   // lo bf16 plane
    __shared__ float s_pa[16][68];
    __shared__ float s_rn[16], s_pinv[16];

    const int tid = threadIdx.x;
    const int w = tid >> 6, quad = (tid >> 4) & 3, n15 = tid & 15;
    const size_t rowBase = (size_t)blockIdx.x * 16;

    // zero pad cols 300..323
    for (int x = tid; x < 16 * 24; x += 512) {
        int r = x / 24, c = 300 + (x - (x / 24) * 24);
        s_h[r][c] = 0; s_l[r][c] = 0;
    }
    // main staging: float4 loads, 8B LDS writes per plane
    for (int x = tid; x < 16 * 75; x += 512) {
        int r = x / 75, c4 = x - r * 75, c = c4 * 4;
        float4 v = *(const float4*)(outbuf + (rowBase + r) * DOUTK + c);
        u16 h0, l0, h1, l1, h2, l2v, h3, l3;
        split_hl(v.x, h0, l0);
        split_hl(v.y, h1, l1);
        split_hl(v.z, h2, l2v);
        split_hl(v.w, h3, l3);
        u16x4 hv = {h0, h1, h2, h3};
        u16x4 lv = {l0, l1, l2v, l3};
        *(u16x4*)&s_h[r][c] = hv;
        *(u16x4*)&s_l[r][c] = lv;
    }
    __syncthreads();

    // ---- pa logits (waves 0-3) || row norms (waves 4-7) ----
    f32x4 accp = {0.f, 0.f, 0.f, 0.f};
    if (w < 4) {
        for (int kk = 0; kk < 10; ++kk) {
            short8 ah = *(const short8*)&s_h[n15][kk * 32 + quad * 8];
            short8 al = *(const short8*)&s_l[n15][kk * 32 + quad * 8];
            short8 b = *(const short8*)(PT + (((kk * 4 + quad) * 64) + (w * 16 + n15)) * 8);
            accp = __builtin_amdgcn_mfma_f32_16x16x32_bf16(ah, b, accp, 0, 0, 0);
            accp = __builtin_amdgcn_mfma_f32_16x16x32_bf16(al, b, accp, 0, 0, 0);
        }
    } else {
        int r = (tid >> 4) & 15, l = tid & 15;
        float s = 0.f;
        for (int i = l; i < 300; i += 16) {
            float v = bf2f(s_h[r][i]) + bf2f(s_l[r][i]);
            s += v * v;
        }
#pragma unroll
        for (int m = 8; m; m >>= 1) s += __shfl_xor(s, m, 64);
        if (l == 0) s_rn[r] = 1.f / fmaxf(sqrtf(s), 1e-12f);
    }
    __syncthreads();
    if (w < 4) {
        int col = w * 16 + n15;
        float pnc = pn[col];
#pragma unroll
        for (int g = 0; g < 4; ++g) {
            int row = quad * 4 + g;
            s_pa[row][col] = __expf(accp[g] * s_rn[row] * pnc);
        }
    }
    __syncthreads();
    if (w >= 4) { // softmax denominators (waves 4-7, 256 threads = 16 rows x 16 lanes)
        int r = (tid >> 4) & 15, l = tid & 15;
        float s = s_pa[r][l] + s_pa[r][l + 16] + s_pa[r][l + 32] + s_pa[r][l + 48];
#pragma unroll
        for (int m = 8; m; m >>= 1) s += __shfl_xor(s, m, 64);
        if (l == 0) s_pinv[r] = 1.f / s;
    }
    __syncthreads();

    // ---- pf: T[16x304] = pa_raw @ proxy; pf = out - T*pinv, in place ----
    f32x4 accf[3];
#pragma unroll
    for (int t = 0; t < 3; ++t) accf[t] = (f32x4){0.f, 0.f, 0.f, 0.f};
    for (int kk = 0; kk < 2; ++kk) {
        short8 ah, al;
        {
            const float* srcp = &s_pa[n15][kk * 32 + quad * 8];
#pragma unroll
            for (int j = 0; j < 8; ++j) {
                float x = srcp[j];
                u32 h = __float_as_uint(x) >> 16;
                float hf = __uint_as_float(h << 16);
                ah[j] = (short)h;
                al[j] = (short)(__float_as_uint(x - hf) >> 16);
            }
        }
#pragma unroll
        for (int t = 0; t < 3; ++t) {
            int nt = w + 8 * t;
            if (nt < 19) {
                short8 b = *(const short8*)(PB + (((kk * 4 + quad) * 304) + (nt * 16 + n15)) * 8);
                accf[t] = __builtin_amdgcn_mfma_f32_16x16x32_bf16(ah, b, accf[t], 0, 0, 0);
                accf[t] = __builtin_amdgcn_mfma_f32_16x16x32_bf16(al, b, accf[t], 0, 0, 0);
            }
        }
    }
#pragma unroll
    for (int t = 0; t < 3; ++t) {
        int nt = w + 8 * t;
        if (nt < 19) {
            int col = nt * 16 + n15;
#pragma unroll
            for (int g = 0; g < 4; ++g) {
                int row = quad * 4 + g;
                float ov = bf2f(s_h[row][col]) + bf2f(s_l[row][col]);
                float v = ov - accf[t][g] * s_pinv[row];
                u16 hh, ll;
                split_hl(v, hh, ll);
                s_h[row][col] = hh;
                s_l[row][col] = ll;
            }
        }
    }
    __syncthreads();

    // ---- gate: Z[16x304] = pf @ gate_k ----
    f32x4 accg[3];
#pragma unroll
    for (int t = 0; t < 3; ++t) accg[t] = (f32x4){0.f, 0.f, 0.f, 0.f};
    for (int kk = 0; kk < 10; ++kk) {
        short8 ah = *(const short8*)&s_h[n15][kk * 32 + quad * 8];
        short8 al = *(const short8*)&s_l[n15][kk * 32 + quad * 8];
#pragma unroll
        for (int t = 0; t < 3; ++t) {
            int nt = w + 8 * t;
            if (nt < 19) {
                short8 b = *(const short8*)(GB + (((kk * 4 + quad) * 304) + (nt * 16 + n15)) * 8);
                accg[t] = __builtin_amdgcn_mfma_f32_16x16x32_bf16(ah, b, accg[t], 0, 0, 0);
                accg[t] = __builtin_amdgcn_mfma_f32_16x16x32_bf16(al, b, accg[t], 0, 0, 0);
            }
        }
    }
    // ---- gated mix + store: res = pv + gate * (accf * pinv) ----
#pragma unroll
    for (int t = 0; t < 3; ++t) {
        int nt = w + 8 * t;
        if (nt < 19) {
            int col = nt * 16 + n15;
            if (col < 300) {
                float bb = bias[col];
#pragma unroll
                for (int g = 0; g < 4; ++g) {
                    int row = quad * 4 + g;
                    float z = accg[t][g] + bb;
                    float gg = 1.f / (1.f + __expf(-z));
                    float pv = bf2f(s_h[row][col]) + bf2f(s_l[row][col]);
                    float res = (pv + gg * accf[t][g] * s_pinv[row]) * alpha;
                    float* o = dout + (rowBase + row) * 600 + col;
                    if (accumulate) res += *o;
                    *o = res;
                }
            }
        }
    }
}

extern "C" void kernel_launch(void* const* d_in, const int* in_sizes, int n_in,
                              void* d_out, int out_size, void* d_ws, size_t ws_size,
                              hipStream_t stream)
{
    const int*   adj      = (const int*)d_in[0];
    const int*   r_index  = (const int*)d_in[1];
    const float* r_val    = (const float*)d_in[2];
    const int*   t_index  = (const int*)d_in[3];
    const int*   ent_adj  = (const int*)d_in[4];
    const int*   rel_adj  = (const int*)d_in[5];
    const int*   time_adj = (const int*)d_in[6];
    const float* ent_emb  = (const float*)d_in[7];
    const float* rel_emb  = (const float*)d_in[8];
    const float* time_emb = (const float*)d_in[9];
    const float* e_attn   = (const float*)d_in[10];
    const float* e_gate   = (const float*)d_in[11];
    const float* e_proxy  = (const float*)d_in[12];
    const float* e_bias   = (const float*)d_in[13];
    const float* r_attn   = (const float*)d_in[14];
    const float* r_gate   = (const float*)d_in[15];
    const float* r_proxy  = (const float*)d_in[16];
    const float* r_bias   = (const float*)d_in[17];
    float* out = (float*)d_out;

    char* ws = (char*)d_ws;
    size_t off = 0;
    auto alloc = [&](size_t bytes) { void* p = ws + off; off += (bytes + 255) & ~255ULL; return p; };
    u16* rels     = (u16*)alloc((size_t)EE * DDIM * 2);       // 80 MB
    float* outbuf = (float*)alloc((size_t)NN * DOUTK * 4);    // 120 MB (also r-CSR scratch while dead)
    float* attE0  = (float*)alloc((size_t)EE * 4);
    float* attE1  = (float*)alloc((size_t)EE * 4);
    float* attR0  = (float*)alloc((size_t)EE * 4);
    float* attR1  = (float*)alloc((size_t)EE * 4);
    float* denE0  = (float*)alloc((size_t)NN * 4);
    float* denE1  = (float*)alloc((size_t)NN * 4);
    float* denR0  = (float*)alloc((size_t)NN * 4);
    float* denR1  = (float*)alloc((size_t)NN * 4);
    int* adjcnt   = (int*)alloc((size_t)NN * 4);
    int* abase    = (int*)alloc((size_t)NN * 4);
    int* acur     = (int*)alloc((size_t)NN * 4);
    int* ecol     = (int*)alloc((size_t)EE * 4);
    int* epos     = (int*)alloc((size_t)EE * 4);
    int* fcnt     = (int*)alloc((size_t)NN * 4);
    int* fbase    = (int*)alloc((size_t)NN * 4);
    int* fcur     = (int*)alloc((size_t)NN * 4);
    int* fcol     = (int*)alloc((size_t)ADJK * 4);
    int* ctr      = (int*)alloc(256);
    float* pnE    = (float*)alloc(64 * 4);
    float* pnR    = (float*)alloc(64 * 4);
    u16* PT_E     = (u16*)alloc(40 * 64 * 8 * 2);
    u16* PT_R     = (u16*)alloc(40 * 64 * 8 * 2);
    u16* PB_E     = (u16*)alloc(8 * 304 * 8 * 2);
    u16* PB_R     = (u16*)alloc(8 * 304 * 8 * 2);
    u16* GB_E     = (u16*)alloc(40 * 304 * 8 * 2);
    u16* GB_R     = (u16*)alloc(40 * 304 * 8 * 2);

    // r/t sparse-index CSR aliased onto outbuf (outbuf is dead whenever rels is (re)built)
    int*   rcnt  = (int*)outbuf;          // EE ints
    int*   rbase = rcnt + EE;             // EE
    int*   rcur  = rbase + EE;            // EE
    int*   rk    = rcur + EE;             // NNZK
    float* rv    = (float*)(rk + NNZK);   // NNZK   -> total 11.2 MB << 120 MB

    proxy_norms<<<1, 64, 0, stream>>>(e_proxy, pnE);
    proxy_norms<<<1, 64, 0, stream>>>(r_proxy, pnR);
    pack_proxyT<<<80, 256, 0, stream>>>(e_proxy, PT_E);
    pack_proxyT<<<80, 256, 0, stream>>>(r_proxy, PT_R);
    pack_proxyB<<<76, 256, 0, stream>>>(e_proxy, PB_E);
    pack_proxyB<<<76, 256, 0, stream>>>(r_proxy, PB_R);
    pack_gateB<<<380, 256, 0, stream>>>(e_gate, GB_E);
    pack_gateB<<<380, 256, 0, stream>>>(r_gate, GB_R);

    // ---- adj CSR (shared by all encoders), built once ----
    hipMemsetAsync(adjcnt, 0, (size_t)NN * 4, stream);
    hipMemsetAsync(ctr, 0, 4, stream);
    k_count<<<(EE + 255) / 256, 256, 0, stream>>>(adj, adjcnt, EE, NN);
    k_alloc<<<(NN + 255) / 256, 256, 0, stream>>>(adjcnt, abase, acur, ctr, NN);
    k_fill<<<(EE + 255) / 256, 256, 0, stream>>>(adj, nullptr, acur, ecol, nullptr, epos, EE, NN);

    auto build_rels = [&](const int* sp, const float* emb, int kMax,
                          const float* attnA, float* aA0, float* aA1, float* dA0, float* dA1,
                          const float* attnB, float* aB0, float* aB1, float* dB0, float* dB1) {
        hipMemsetAsync(rcnt, 0, (size_t)EE * 4, stream);
        hipMemsetAsync(ctr, 0, 4, stream);
        hipMemsetAsync(dA0, 0, (size_t)NN * 4, stream);
        hipMemsetAsync(dA1, 0, (size_t)NN * 4, stream);
        if (attnB) {
            hipMemsetAsync(dB0, 0, (size_t)NN * 4, stream);
            hipMemsetAsync(dB1, 0, (size_t)NN * 4, stream);
        }
        k_count<<<(NNZK + 255) / 256, 256, 0, stream>>>(sp, rcnt, NNZK, EE);
        k_alloc<<<(EE + 255) / 256, 256, 0, stream>>>(rcnt, rbase, rcur, ctr, EE);
        k_fill<<<(NNZK + 255) / 256, 256, 0, stream>>>(sp, r_val, rcur, rk, rv, nullptr, NNZK, EE);
        rels_build<<<(EE + 3) / 4, 256, 0, stream>>>(rbase, rcnt, rk, rv, epos, adj, emb, rels,
                                                     attnA, aA0, aA1, dA0, dA1,
                                                     attnB, aB0, aB1, dB0, dB1, kMax, EE);
    };

    struct Enc {
        const int* fadj; const float* femb; int colMax;
        const float* a0; const float* a1; const float* d0; const float* d1;
        const u16* PT; const u16* PB; const u16* GB; const float* pn; const float* bias;
        int dcol; float alpha; int accum;
    };
    Enc encs[3] = {
        { ent_adj,  ent_emb,  NN,   attE0, attE1, denE0, denE1, PT_E, PB_E, GB_E, pnE, e_bias,   0, 1.0f, 0 },
        { rel_adj,  rel_emb,  2000, attR0, attR1, denR0, denR1, PT_R, PB_R, GB_R, pnR, r_bias, 300, 0.5f, 0 },
        { time_adj, time_emb, 1000, attE0, attE1, denE0, denE1, PT_E, PB_E, GB_E, pnE, e_bias, 300, 0.5f, 1 },
    };

    const int rw_grid = (NN + 3) / 4;   // wave-per-row grids

    // relsR: used by enc 0 (e_attn set) and enc 1 (r_attn set)
    build_rels(r_index, rel_emb, 2000,
               e_attn, attE0, attE1, denE0, denE1,
               r_attn, attR0, attR1, denR0, denR1);
    for (int c = 0; c < 3; ++c) {
        if (c == 2) {
            // relsT replaces relsR (outbuf dead here); e_attn set reused for T
            build_rels(t_index, time_emb, 1000,
                       e_attn, attE0, attE1, denE0, denE1,
                       nullptr, nullptr, nullptr, nullptr, nullptr);
        }
        const Enc& e = encs[c];

        // feature-adjacency CSR for this encoder
        hipMemsetAsync(fcnt, 0, (size_t)NN * 4, stream);
        hipMemsetAsync(ctr, 0, 4, stream);
        k_count<<<(ADJK + 255) / 256, 256, 0, stream>>>(e.fadj, fcnt, ADJK, NN);
        k_alloc<<<(NN + 255) / 256, 256, 0, stream>>>(fcnt, fbase, fcur, ctr, NN);
        k_fill<<<(ADJK + 255) / 256, 256, 0, stream>>>(e.fadj, nullptr, fcur, fcol, nullptr, nullptr, ADJK, NN);

        feat_gather<<<rw_grid, 256, 0, stream>>>(fbase, fcnt, fcol, e.femb, outbuf, e.colMax, NN);
        mp_layer<<<rw_grid, 256, 0, stream>>>(abase, adjcnt, ecol, rels, e.a0, e.d0,
                                              outbuf, outbuf + DDIM, NN);
        mp_layer<<<rw_grid, 256, 0, stream>>>(abase, adjcnt, ecol, rels, e.a1, e.d1,
                                              outbuf + DDIM, outbuf + 2 * DDIM, NN);
        epilogue_mfma<<<NN / 16, 512, 0, stream>>>(outbuf, e.PT, e.PB, e.GB, e.pn, e.bias,
                                                   out + e.dcol, e.alpha, e.accum);
    }
}

// Round 6
// 2206.624 us; speedup vs baseline: 3.3202x; 1.1407x over previous
//
#include <hip/hip_runtime.h>
#include <stdint.h>

#define NN    100000
#define EE    400000
#define NNZK  800000
#define ADJK  400000
#define DDIM  100
#define DOUTK 300

typedef unsigned short u16;
typedef unsigned int   u32;
typedef __attribute__((ext_vector_type(8))) short short8;
typedef __attribute__((ext_vector_type(4))) float f32x4;
typedef __attribute__((ext_vector_type(4))) unsigned short u16x4;

__device__ __forceinline__ float bf2f(u16 b) { return __uint_as_float(((u32)b) << 16); }
__device__ __forceinline__ u16 f2bf(float x) {
    u32 u = __float_as_uint(x);
    u32 r = (u + 0x7FFFu + ((u >> 16) & 1u)) >> 16;  // RNE
    return (u16)r;
}
// truncation hi/lo split: x ~= bf(hi) + bf(lo) to ~2^-17 rel
__device__ __forceinline__ void split_hl(float x, u16& h, u16& l) {
    u32 u = __float_as_uint(x);
    h = (u16)(u >> 16);
    float hf = __uint_as_float(u & 0xFFFF0000u);
    l = (u16)(__float_as_uint(x - hf) >> 16);
}

// ================= CSR building (int atomics only) =================

__global__ __launch_bounds__(256) void k_count(
    const int* __restrict__ idx, int* __restrict__ cnt, int nnz, int kmax)
{
    int i = blockIdx.x * 256 + threadIdx.x;
    if (i >= nnz) return;
    int key = idx[2 * i];
    if (key < 0 || key >= kmax) return;
    atomicAdd(&cnt[key], 1);
}

__global__ __launch_bounds__(256) void k_alloc(
    const int* __restrict__ cnt, int* __restrict__ base, int* __restrict__ cur,
    int* __restrict__ ctr, int n)
{
    int i = blockIdx.x * 256 + threadIdx.x;
    int lane = threadIdx.x & 63;
    int c = (i < n) ? cnt[i] : 0;
    int s = c;
#pragma unroll
    for (int m = 1; m < 64; m <<= 1) {
        int t = __shfl_up(s, m, 64);
        if (lane >= m) s += t;
    }
    int total = __shfl(s, 63, 64);
    int wbase = 0;
    if (lane == 63) wbase = atomicAdd(ctr, total);
    wbase = __shfl(wbase, 63, 64);
    int b = wbase + s - c;   // exclusive within wave
    if (i < n) { base[i] = b; cur[i] = b; }
}

__global__ __launch_bounds__(256) void k_fill(
    const int* __restrict__ idx, const float* __restrict__ val, int* __restrict__ cur,
    int* __restrict__ ocol, float* __restrict__ oval, int* __restrict__ opos,
    int nnz, int kmax)
{
    int i = blockIdx.x * 256 + threadIdx.x;
    if (i >= nnz) return;
    int key = idx[2 * i];
    if (key < 0 || key >= kmax) return;
    int p = atomicAdd(&cur[key], 1);
    ocol[p] = idx[2 * i + 1];
    if (oval) oval[p] = val[i];
    if (opos) opos[i] = p;
}

// ================= rels build + fused attention logits =================
// ONE 32-LANE GROUP PER EDGE (8 edges/block): 4 dims/lane, lanes 0..24 active.
// gathers val*emb, l2-normalizes in regs, writes bf16 rels at CSR position,
// computes exp(dot(rels, attn[l])) for up to two attn sets; per-row softmax
// denominators accumulated via float atomics (group lane 0).
__global__ __launch_bounds__(256) void rels_build(
    const int* __restrict__ base, const int* __restrict__ cnt,
    const int* __restrict__ rk, const float* __restrict__ rv,
    const int* __restrict__ epos, const int* __restrict__ adjr,
    const float* __restrict__ emb, u16* __restrict__ rels,
    const float* __restrict__ attnA, float* __restrict__ attA0, float* __restrict__ attA1,
    float* __restrict__ denA0, float* __restrict__ denA1,
    const float* __restrict__ attnB, float* __restrict__ attB0, float* __restrict__ attB1,
    float* __restrict__ denB0, float* __restrict__ denB1,
    int kMax, int nE)
{
    int e = blockIdx.x * 8 + (threadIdx.x >> 5);
    if (e >= nE) return;
    int gl = threadIdx.x & 31;
    bool act = gl < 25;
    int d4 = gl * 4;
    int st = base[e], k = cnt[e];
    bool hasB = (attnB != nullptr);

    float4 acc = {0.f, 0.f, 0.f, 0.f};
    for (int j = 0; j < k; ++j) {
        int kk = rk[st + j];
        if (kk < 0 || kk >= kMax) continue;
        float v = rv[st + j];
        if (act) {
            float4 ev = *(const float4*)(emb + (size_t)kk * DDIM + d4);
            acc.x += v * ev.x; acc.y += v * ev.y;
            acc.z += v * ev.z; acc.w += v * ev.w;
        }
    }
    float4 aA0 = {0.f,0.f,0.f,0.f}, aA1 = {0.f,0.f,0.f,0.f};
    float4 aB0 = {0.f,0.f,0.f,0.f}, aB1 = {0.f,0.f,0.f,0.f};
    if (act) {
        aA0 = *(const float4*)(attnA + d4);
        aA1 = *(const float4*)(attnA + DDIM + d4);
        if (hasB) {
            aB0 = *(const float4*)(attnB + d4);
            aB1 = *(const float4*)(attnB + DDIM + d4);
        }
    }
    float s   = acc.x*acc.x + acc.y*acc.y + acc.z*acc.z + acc.w*acc.w;
    float dA0 = acc.x*aA0.x + acc.y*aA0.y + acc.z*aA0.z + acc.w*aA0.w;
    float dA1 = acc.x*aA1.x + acc.y*aA1.y + acc.z*aA1.z + acc.w*aA1.w;
#pragma unroll
    for (int m = 1; m <= 16; m <<= 1) {   // masks < 32: stays within the 32-group
        s   += __shfl_xor(s, m, 64);
        dA0 += __shfl_xor(dA0, m, 64);
        dA1 += __shfl_xor(dA1, m, 64);
    }
    float dB0 = 0.f, dB1 = 0.f;
    if (hasB) {
        dB0 = acc.x*aB0.x + acc.y*aB0.y + acc.z*aB0.z + acc.w*aB0.w;
        dB1 = acc.x*aB1.x + acc.y*aB1.y + acc.z*aB1.z + acc.w*aB1.w;
#pragma unroll
        for (int m = 1; m <= 16; m <<= 1) {
            dB0 += __shfl_xor(dB0, m, 64);
            dB1 += __shfl_xor(dB1, m, 64);
        }
    }
    float sc = 1.f / fmaxf(sqrtf(s), 1e-12f);
    int ep = epos[e];
    if (act) {
        u16x4 pk;
        pk[0] = f2bf(acc.x * sc); pk[1] = f2bf(acc.y * sc);
        pk[2] = f2bf(acc.z * sc); pk[3] = f2bf(acc.w * sc);
        *(u16x4*)(rels + (size_t)ep * DDIM + d4) = pk;
    }
    if (gl == 0) {
        int row = adjr[2 * e];
        bool rok = (row >= 0 && row < NN);
        float eA0 = __expf(dA0 * sc), eA1 = __expf(dA1 * sc);
        attA0[ep] = eA0; attA1[ep] = eA1;
        if (rok) { atomicAdd(&denA0[row], eA0); atomicAdd(&denA1[row], eA1); }
        if (hasB) {
            float eB0 = __expf(dB0 * sc), eB1 = __expf(dB1 * sc);
            attB0[ep] = eB0; attB1[ep] = eB1;
            if (rok) { atomicAdd(&denB0[row], eB0); atomicAdd(&denB1[row], eB1); }
        }
    }
}

// ================= feature mean-aggregation gather (fused tanh) ==============
// ONE 32-LANE GROUP PER ROW (8 rows/block): 4 dims/lane, lanes 0..24 active.
__global__ __launch_bounds__(256) void feat_gather(
    const int* __restrict__ base, const int* __restrict__ cnt, const int* __restrict__ fcol,
    const float* __restrict__ emb, float* __restrict__ dst, int colMax, int nRows)
{
    int w = blockIdx.x * 8 + (threadIdx.x >> 5);
    if (w >= nRows) return;
    int gl = threadIdx.x & 31;
    bool act = gl < 25;
    int d4 = gl * 4;
    int st = base[w], k = cnt[w];
    float4 acc = {0.f, 0.f, 0.f, 0.f};
    for (int j = 0; j < k; ++j) {
        int col = fcol[st + j];
        if (col < 0 || col >= colMax) continue;
        if (act) {
            float4 ev = *(const float4*)(emb + (size_t)col * DDIM + d4);
            acc.x += ev.x; acc.y += ev.y; acc.z += ev.z; acc.w += ev.w;
        }
    }
    float inv = k ? 1.f / (float)k : 0.f;
    if (act) {
        float4 o;
        o.x = tanhf(acc.x * inv); o.y = tanhf(acc.y * inv);
        o.z = tanhf(acc.z * inv); o.w = tanhf(acc.w * inv);
        *(float4*)(dst + (size_t)w * DOUTK + d4) = o;
    }
}

// ================= message-passing layer (gather, precomputed att/den) ========
// one wave per row; TWO EDGES PER LOOP STEP (one per 32-lane group, 4 dims/lane);
// group partial sums combined with one xor-32 shuffle at the end.
__global__ __launch_bounds__(256) void mp_layer(
    const int* __restrict__ base, const int* __restrict__ cnt, const int* __restrict__ ecol,
    const u16* __restrict__ rels, const float* __restrict__ att, const float* __restrict__ den,
    const float* __restrict__ src, float* __restrict__ dst, int nRows)
{
    int w = blockIdx.x * 4 + (threadIdx.x >> 6);
    if (w >= nRows) return;
    int lane = threadIdx.x & 63;
    int g = lane >> 5, gl = lane & 31;
    bool act = gl < 25;
    int d4 = gl * 4;
    int st = base[w], k = cnt[w];
    float d = den[w];
    float inv = (d > 0.f) ? 1.f / d : 0.f;
    float4 acc = {0.f, 0.f, 0.f, 0.f};
    for (int j = 0; j < k; j += 2) {
        int je = j + g;
        int col = -1;
        if (je < k) col = ecol[st + je];
        bool cok = (col >= 0 && col < NN);
        float4 r = {0.f,0.f,0.f,0.f}, f = {0.f,0.f,0.f,0.f};
        if (cok && act) {
            u16x4 rr = *(const u16x4*)(rels + (size_t)(st + je) * DDIM + d4);
            r.x = bf2f(rr[0]); r.y = bf2f(rr[1]);
            r.z = bf2f(rr[2]); r.w = bf2f(rr[3]);
            f = *(const float4*)(src + (size_t)col * DOUTK + d4);
        }
        float pd = f.x*r.x + f.y*r.y + f.z*r.z + f.w*r.w;
#pragma unroll
        for (int m = 1; m <= 16; m <<= 1) pd += __shfl_xor(pd, m, 64);  // within-group
        float a = cok ? att[st + je] * inv : 0.f;
        float c2 = 2.f * pd;
        acc.x += a * (f.x - c2 * r.x);
        acc.y += a * (f.y - c2 * r.y);
        acc.z += a * (f.z - c2 * r.z);
        acc.w += a * (f.w - c2 * r.w);
    }
    // combine the two groups' partial sums (even edges + odd edges)
    acc.x += __shfl_xor(acc.x, 32, 64);
    acc.y += __shfl_xor(acc.y, 32, 64);
    acc.z += __shfl_xor(acc.z, 32, 64);
    acc.w += __shfl_xor(acc.w, 32, 64);
    if (g == 0 && act) {
        float4 o;
        o.x = tanhf(acc.x); o.y = tanhf(acc.y);
        o.z = tanhf(acc.z); o.w = tanhf(acc.w);
        *(float4*)(dst + (size_t)w * DOUTK + d4) = o;
    }
}

// ---- inverse norms of proxy rows ----
__global__ __launch_bounds__(64) void proxy_norms(const float* __restrict__ proxy, float* __restrict__ pn)
{
    int k = threadIdx.x;
    if (k >= 64) return;
    float s = 0.f;
    for (int i = 0; i < DOUTK; ++i) { float v = proxy[k * DOUTK + i]; s += v * v; }
    pn[k] = 1.f / fmaxf(sqrtf(s), 1e-12f);
}

// ---- weight prepack kernels: fp32 -> frag-order bf16 [ktile][n][8] ----
__global__ __launch_bounds__(256) void pack_proxyT(const float* __restrict__ p, u16* __restrict__ o)
{
    int t = blockIdx.x * 256 + threadIdx.x;
    if (t >= 40 * 64 * 8) return;
    int j = t & 7, n = (t >> 3) & 63, kt = t >> 9;
    int k = kt * 8 + j;
    o[t] = f2bf((k < 300) ? p[n * 300 + k] : 0.f);
}
__global__ __launch_bounds__(256) void pack_proxyB(const float* __restrict__ p, u16* __restrict__ o)
{
    int t = blockIdx.x * 256 + threadIdx.x;
    if (t >= 8 * 304 * 8) return;
    int j = t & 7, n = (t >> 3) % 304, kt = t / (304 * 8);
    int k = kt * 8 + j;
    o[t] = f2bf((k < 64 && n < 300) ? p[k * 300 + n] : 0.f);
}
__global__ __launch_bounds__(256) void pack_gateB(const float* __restrict__ p, u16* __restrict__ o)
{
    int t = blockIdx.x * 256 + threadIdx.x;
    if (t >= 40 * 304 * 8) return;
    int j = t & 7, n = (t >> 3) % 304, kt = t / (304 * 8);
    int k = kt * 8 + j;
    o[t] = f2bf((k < 300 && n < 300) ? p[k * 300 + n] : 0.f);
}

// ---- MFMA epilogue: 16 rows/block, 512 threads (8 waves), 3 tiles/wave ----
// layouts (16x16x32 bf16): A[m=lane&15][k=quad*8+j]; C/D col=lane&15,row=quad*4+reg
// waves 0-3: pa GEMM; waves 4-7: row norms (concurrent). Final mix uses
// res = pv + gate*(accf*pinv) (ov never stored: ov-pv == T*pinv).
__global__ __launch_bounds__(512, 6) void epilogue_mfma(
    const float* __restrict__ outbuf, const u16* __restrict__ PT, const u16* __restrict__ PB,
    const u16* __restrict__ GB, const float* __restrict__ pn, const float* __restrict__ bias,
    float* __restrict__ dout, float alpha, int accumulate)
{
    __shared__ u16 s_h[16][324];   // hi bf16 plane: out, later pf
    __shared__ u16 s_l[16][324];   // lo bf16 plane
    __shared__ float s_pa[16][68];
    __shared__ float s_rn[16], s_pinv[16];

    const int tid = threadIdx.x;
    const int w = tid >> 6, quad = (tid >> 4) & 3, n15 = tid & 15;
    const size_t rowBase = (size_t)blockIdx.x * 16;

    // zero pad cols 300..323
    for (int x = tid; x < 16 * 24; x += 512) {
        int r = x / 24, c = 300 + (x - (x / 24) * 24);
        s_h[r][c] = 0; s_l[r][c] = 0;
    }
    // main staging: float4 loads, 8B LDS writes per plane
    for (int x = tid; x < 16 * 75; x += 512) {
        int r = x / 75, c4 = x - r * 75, c = c4 * 4;
        float4 v = *(const float4*)(outbuf + (rowBase + r) * DOUTK + c);
        u16 h0, l0, h1, l1, h2, l2v, h3, l3;
        split_hl(v.x, h0, l0);
        split_hl(v.y, h1, l1);
        split_hl(v.z, h2, l2v);
        split_hl(v.w, h3, l3);
        u16x4 hv = {h0, h1, h2, h3};
        u16x4 lv = {l0, l1, l2v, l3};
        *(u16x4*)&s_h[r][c] = hv;
        *(u16x4*)&s_l[r][c] = lv;
    }
    __syncthreads();

    // ---- pa logits (waves 0-3) || row norms (waves 4-7) ----
    f32x4 accp = {0.f, 0.f, 0.f, 0.f};
    if (w < 4) {
        for (int kk = 0; kk < 10; ++kk) {
            short8 ah = *(const short8*)&s_h[n15][kk * 32 + quad * 8];
            short8 al = *(const short8*)&s_l[n15][kk * 32 + quad * 8];
            short8 b = *(const short8*)(PT + (((kk * 4 + quad) * 64) + (w * 16 + n15)) * 8);
            accp = __builtin_amdgcn_mfma_f32_16x16x32_bf16(ah, b, accp, 0, 0, 0);
            accp = __builtin_amdgcn_mfma_f32_16x16x32_bf16(al, b, accp, 0, 0, 0);
        }
    } else {
        int r = (tid >> 4) & 15, l = tid & 15;
        float s = 0.f;
        for (int i = l; i < 300; i += 16) {
            float v = bf2f(s_h[r][i]) + bf2f(s_l[r][i]);
            s += v * v;
        }
#pragma unroll
        for (int m = 8; m; m >>= 1) s += __shfl_xor(s, m, 64);
        if (l == 0) s_rn[r] = 1.f / fmaxf(sqrtf(s), 1e-12f);
    }
    __syncthreads();
    if (w < 4) {
        int col = w * 16 + n15;
        float pnc = pn[col];
#pragma unroll
        for (int g = 0; g < 4; ++g) {
            int row = quad * 4 + g;
            s_pa[row][col] = __expf(accp[g] * s_rn[row] * pnc);
        }
    }
    __syncthreads();
    if (w >= 4) { // softmax denominators (waves 4-7, 256 threads = 16 rows x 16 lanes)
        int r = (tid >> 4) & 15, l = tid & 15;
        float s = s_pa[r][l] + s_pa[r][l + 16] + s_pa[r][l + 32] + s_pa[r][l + 48];
#pragma unroll
        for (int m = 8; m; m >>= 1) s += __shfl_xor(s, m, 64);
        if (l == 0) s_pinv[r] = 1.f / s;
    }
    __syncthreads();

    // ---- pf: T[16x304] = pa_raw @ proxy; pf = out - T*pinv, in place ----
    f32x4 accf[3];
#pragma unroll
    for (int t = 0; t < 3; ++t) accf[t] = (f32x4){0.f, 0.f, 0.f, 0.f};
    for (int kk = 0; kk < 2; ++kk) {
        short8 ah, al;
        {
            const float* srcp = &s_pa[n15][kk * 32 + quad * 8];
#pragma unroll
            for (int j = 0; j < 8; ++j) {
                float x = srcp[j];
                u32 h = __float_as_uint(x) >> 16;
                float hf = __uint_as_float(h << 16);
                ah[j] = (short)h;
                al[j] = (short)(__float_as_uint(x - hf) >> 16);
            }
        }
#pragma unroll
        for (int t = 0; t < 3; ++t) {
            int nt = w + 8 * t;
            if (nt < 19) {
                short8 b = *(const short8*)(PB + (((kk * 4 + quad) * 304) + (nt * 16 + n15)) * 8);
                accf[t] = __builtin_amdgcn_mfma_f32_16x16x32_bf16(ah, b, accf[t], 0, 0, 0);
                accf[t] = __builtin_amdgcn_mfma_f32_16x16x32_bf16(al, b, accf[t], 0, 0, 0);
            }
        }
    }
#pragma unroll
    for (int t = 0; t < 3; ++t) {
        int nt = w + 8 * t;
        if (nt < 19) {
            int col = nt * 16 + n15;
#pragma unroll
            for (int g = 0; g < 4; ++g) {
                int row = quad * 4 + g;
                float ov = bf2f(s_h[row][col]) + bf2f(s_l[row][col]);
                float v = ov - accf[t][g] * s_pinv[row];
                u16 hh, ll;
                split_hl(v, hh, ll);
                s_h[row][col] = hh;
                s_l[row][col] = ll;
            }
        }
    }
    __syncthreads();

    // ---- gate: Z[16x304] = pf @ gate_k ----
    f32x4 accg[3];
#pragma unroll
    for (int t = 0; t < 3; ++t) accg[t] = (f32x4){0.f, 0.f, 0.f, 0.f};
    for (int kk = 0; kk < 10; ++kk) {
        short8 ah = *(const short8*)&s_h[n15][kk * 32 + quad * 8];
        short8 al = *(const short8*)&s_l[n15][kk * 32 + quad * 8];
#pragma unroll
        for (int t = 0; t < 3; ++t) {
            int nt = w + 8 * t;
            if (nt < 19) {
                short8 b = *(const short8*)(GB + (((kk * 4 + quad) * 304) + (nt * 16 + n15)) * 8);
                accg[t] = __builtin_amdgcn_mfma_f32_16x16x32_bf16(ah, b, accg[t], 0, 0, 0);
                accg[t] = __builtin_amdgcn_mfma_f32_16x16x32_bf16(al, b, accg[t], 0, 0, 0);
            }
        }
    }
    // ---- gated mix + store: res = pv + gate * (accf * pinv) ----
#pragma unroll
    for (int t = 0; t < 3; ++t) {
        int nt = w + 8 * t;
        if (nt < 19) {
            int col = nt * 16 + n15;
            if (col < 300) {
                float bb = bias[col];
#pragma unroll
                for (int g = 0; g < 4; ++g) {
                    int row = quad * 4 + g;
                    float z = accg[t][g] + bb;
                    float gg = 1.f / (1.f + __expf(-z));
                    float pv = bf2f(s_h[row][col]) + bf2f(s_l[row][col]);
                    float res = (pv + gg * accf[t][g] * s_pinv[row]) * alpha;
                    float* o = dout + (rowBase + row) * 600 + col;
                    if (accumulate) res += *o;
                    *o = res;
                }
            }
        }
    }
}

extern "C" void kernel_launch(void* const* d_in, const int* in_sizes, int n_in,
                              void* d_out, int out_size, void* d_ws, size_t ws_size,
                              hipStream_t stream)
{
    const int*   adj      = (const int*)d_in[0];
    const int*   r_index  = (const int*)d_in[1];
    const float* r_val    = (const float*)d_in[2];
    const int*   t_index  = (const int*)d_in[3];
    const int*   ent_adj  = (const int*)d_in[4];
    const int*   rel_adj  = (const int*)d_in[5];
    const int*   time_adj = (const int*)d_in[6];
    const float* ent_emb  = (const float*)d_in[7];
    const float* rel_emb  = (const float*)d_in[8];
    const float* time_emb = (const float*)d_in[9];
    const float* e_attn   = (const float*)d_in[10];
    const float* e_gate   = (const float*)d_in[11];
    const float* e_proxy  = (const float*)d_in[12];
    const float* e_bias   = (const float*)d_in[13];
    const float* r_attn   = (const float*)d_in[14];
    const float* r_gate   = (const float*)d_in[15];
    const float* r_proxy  = (const float*)d_in[16];
    const float* r_bias   = (const float*)d_in[17];
    float* out = (float*)d_out;

    char* ws = (char*)d_ws;
    size_t off = 0;
    auto alloc = [&](size_t bytes) { void* p = ws + off; off += (bytes + 255) & ~255ULL; return p; };
    u16* rels     = (u16*)alloc((size_t)EE * DDIM * 2);       // 80 MB
    float* outbuf = (float*)alloc((size_t)NN * DOUTK * 4);    // 120 MB (also r-CSR scratch while dead)
    float* attE0  = (float*)alloc((size_t)EE * 4);
    float* attE1  = (float*)alloc((size_t)EE * 4);
    float* attR0  = (float*)alloc((size_t)EE * 4);
    float* attR1  = (float*)alloc((size_t)EE * 4);
    float* denE0  = (float*)alloc((size_t)NN * 4);
    float* denE1  = (float*)alloc((size_t)NN * 4);
    float* denR0  = (float*)alloc((size_t)NN * 4);
    float* denR1  = (float*)alloc((size_t)NN * 4);
    int* adjcnt   = (int*)alloc((size_t)NN * 4);
    int* abase    = (int*)alloc((size_t)NN * 4);
    int* acur     = (int*)alloc((size_t)NN * 4);
    int* ecol     = (int*)alloc((size_t)EE * 4);
    int* epos     = (int*)alloc((size_t)EE * 4);
    int* fcnt     = (int*)alloc((size_t)NN * 4);
    int* fbase    = (int*)alloc((size_t)NN * 4);
    int* fcur     = (int*)alloc((size_t)NN * 4);
    int* fcol     = (int*)alloc((size_t)ADJK * 4);
    int* ctr      = (int*)alloc(256);
    float* pnE    = (float*)alloc(64 * 4);
    float* pnR    = (float*)alloc(64 * 4);
    u16* PT_E     = (u16*)alloc(40 * 64 * 8 * 2);
    u16* PT_R     = (u16*)alloc(40 * 64 * 8 * 2);
    u16* PB_E     = (u16*)alloc(8 * 304 * 8 * 2);
    u16* PB_R     = (u16*)alloc(8 * 304 * 8 * 2);
    u16* GB_E     = (u16*)alloc(40 * 304 * 8 * 2);
    u16* GB_R     = (u16*)alloc(40 * 304 * 8 * 2);

    // r/t sparse-index CSR aliased onto outbuf (outbuf is dead whenever rels is (re)built)
    int*   rcnt  = (int*)outbuf;          // EE ints
    int*   rbase = rcnt + EE;             // EE
    int*   rcur  = rbase + EE;            // EE
    int*   rk    = rcur + EE;             // NNZK
    float* rv    = (float*)(rk + NNZK);   // NNZK   -> total 11.2 MB << 120 MB

    proxy_norms<<<1, 64, 0, stream>>>(e_proxy, pnE);
    proxy_norms<<<1, 64, 0, stream>>>(r_proxy, pnR);
    pack_proxyT<<<80, 256, 0, stream>>>(e_proxy, PT_E);
    pack_proxyT<<<80, 256, 0, stream>>>(r_proxy, PT_R);
    pack_proxyB<<<76, 256, 0, stream>>>(e_proxy, PB_E);
    pack_proxyB<<<76, 256, 0, stream>>>(r_proxy, PB_R);
    pack_gateB<<<380, 256, 0, stream>>>(e_gate, GB_E);
    pack_gateB<<<380, 256, 0, stream>>>(r_gate, GB_R);

    // ---- adj CSR (shared by all encoders), built once ----
    hipMemsetAsync(adjcnt, 0, (size_t)NN * 4, stream);
    hipMemsetAsync(ctr, 0, 4, stream);
    k_count<<<(EE + 255) / 256, 256, 0, stream>>>(adj, adjcnt, EE, NN);
    k_alloc<<<(NN + 255) / 256, 256, 0, stream>>>(adjcnt, abase, acur, ctr, NN);
    k_fill<<<(EE + 255) / 256, 256, 0, stream>>>(adj, nullptr, acur, ecol, nullptr, epos, EE, NN);

    auto build_rels = [&](const int* sp, const float* emb, int kMax,
                          const float* attnA, float* aA0, float* aA1, float* dA0, float* dA1,
                          const float* attnB, float* aB0, float* aB1, float* dB0, float* dB1) {
        hipMemsetAsync(rcnt, 0, (size_t)EE * 4, stream);
        hipMemsetAsync(ctr, 0, 4, stream);
        hipMemsetAsync(dA0, 0, (size_t)NN * 4, stream);
        hipMemsetAsync(dA1, 0, (size_t)NN * 4, stream);
        if (attnB) {
            hipMemsetAsync(dB0, 0, (size_t)NN * 4, stream);
            hipMemsetAsync(dB1, 0, (size_t)NN * 4, stream);
        }
        k_count<<<(NNZK + 255) / 256, 256, 0, stream>>>(sp, rcnt, NNZK, EE);
        k_alloc<<<(EE + 255) / 256, 256, 0, stream>>>(rcnt, rbase, rcur, ctr, EE);
        k_fill<<<(NNZK + 255) / 256, 256, 0, stream>>>(sp, r_val, rcur, rk, rv, nullptr, NNZK, EE);
        rels_build<<<(EE + 7) / 8, 256, 0, stream>>>(rbase, rcnt, rk, rv, epos, adj, emb, rels,
                                                     attnA, aA0, aA1, dA0, dA1,
                                                     attnB, aB0, aB1, dB0, dB1, kMax, EE);
    };

    struct Enc {
        const int* fadj; const float* femb; int colMax;
        const float* a0; const float* a1; const float* d0; const float* d1;
        const u16* PT; const u16* PB; const u16* GB; const float* pn; const float* bias;
        int dcol; float alpha; int accum;
    };
    Enc encs[3] = {
        { ent_adj,  ent_emb,  NN,   attE0, attE1, denE0, denE1, PT_E, PB_E, GB_E, pnE, e_bias,   0, 1.0f, 0 },
        { rel_adj,  rel_emb,  2000, attR0, attR1, denR0, denR1, PT_R, PB_R, GB_R, pnR, r_bias, 300, 0.5f, 0 },
        { time_adj, time_emb, 1000, attE0, attE1, denE0, denE1, PT_E, PB_E, GB_E, pnE, e_bias, 300, 0.5f, 1 },
    };

    // relsR: used by enc 0 (e_attn set) and enc 1 (r_attn set)
    build_rels(r_index, rel_emb, 2000,
               e_attn, attE0, attE1, denE0, denE1,
               r_attn, attR0, attR1, denR0, denR1);
    for (int c = 0; c < 3; ++c) {
        if (c == 2) {
            // relsT replaces relsR (outbuf dead here); e_attn set reused for T
            build_rels(t_index, time_emb, 1000,
                       e_attn, attE0, attE1, denE0, denE1,
                       nullptr, nullptr, nullptr, nullptr, nullptr);
        }
        const Enc& e = encs[c];

        // feature-adjacency CSR for this encoder
        hipMemsetAsync(fcnt, 0, (size_t)NN * 4, stream);
        hipMemsetAsync(ctr, 0, 4, stream);
        k_count<<<(ADJK + 255) / 256, 256, 0, stream>>>(e.fadj, fcnt, ADJK, NN);
        k_alloc<<<(NN + 255) / 256, 256, 0, stream>>>(fcnt, fbase, fcur, ctr, NN);
        k_fill<<<(ADJK + 255) / 256, 256, 0, stream>>>(e.fadj, nullptr, fcur, fcol, nullptr, nullptr, ADJK, NN);

        feat_gather<<<(NN + 7) / 8, 256, 0, stream>>>(fbase, fcnt, fcol, e.femb, outbuf, e.colMax, NN);
        mp_layer<<<(NN + 3) / 4, 256, 0, stream>>>(abase, adjcnt, ecol, rels, e.a0, e.d0,
                                                   outbuf, outbuf + DDIM, NN);
        mp_layer<<<(NN + 3) / 4, 256, 0, stream>>>(abase, adjcnt, ecol, rels, e.a1, e.d1,
                                                   outbuf + DDIM, outbuf + 2 * DDIM, NN);
        epilogue_mfma<<<NN / 16, 512, 0, stream>>>(outbuf, e.PT, e.PB, e.GB, e.pn, e.bias,
                                                   out + e.dcol, e.alpha, e.accum);
    }
}